// Round 3
// baseline (2543.058 us; speedup 1.0000x reference)
//
#include <hip/hip_runtime.h>

#define L_NUM 2
#define H_NUM 8
#define D_DIM 64
#define HID_D 512
#define FF_D  2048
#define S_SEQ 256
#define B_NUM 8

// ---------------------------------------------------------------------------
// Per-head softmax: h (S,B,HID) f32 -> xs (B,H,S,D) f32. One wave per 64-row.
// ---------------------------------------------------------------------------
__global__ __launch_bounds__(256) void softmax_xs_k(
    const float* __restrict__ h, float* __restrict__ xs)
{
  int rid  = blockIdx.x*4 + (threadIdx.x>>6);   // (s*B+b)*H + hd
  int lane = threadIdx.x & 63;
  int hd = rid & (H_NUM-1);
  int sb = rid >> 3;                            // s*B + b
  int b  = sb & (B_NUM-1);
  int s  = sb >> 3;
  float v = h[(size_t)sb*HID_D + hd*D_DIM + lane];
  float m = v;
  #pragma unroll
  for (int off=32; off; off>>=1) m = fmaxf(m, __shfl_xor(m, off));
  float e = __expf(v-m);
  float sum = e;
  #pragma unroll
  for (int off=32; off; off>>=1) sum += __shfl_xor(sum, off);
  xs[(((size_t)(b*H_NUM+hd))*S_SEQ + s)*D_DIM + lane] = e/sum;
}

// ---------------------------------------------------------------------------
// SRWM sequential scan — ONE WAVE per (b,h). Lane i owns row i of Wy,Wq,Wk
// (192 VGPRs) and row i of wb. Zero barriers; butterflies for all scalar
// reduces; LDS only for broadcasting d and k vectors within the wave.
// ---------------------------------------------------------------------------
__global__ __launch_bounds__(64,1) void scan1_k(
    const float* __restrict__ xs,                 // (B,H,S,D) f32
    const float* __restrict__ st_y, const float* __restrict__ st_q,
    const float* __restrict__ st_k, const float* __restrict__ st_b,
    const float* __restrict__ p_y,  const float* __restrict__ p_q,
    const float* __restrict__ p_k,  const float* __restrict__ p_b,
    float* __restrict__ y_out,                    // (S,B,HID) f32
    float* __restrict__ o_sy, float* __restrict__ o_sq,
    float* __restrict__ o_sk, float* __restrict__ o_sb)
{
  const int bh = blockIdx.x;
  const int b  = bh >> 3, hh = bh & 7;
  const int lane = threadIdx.x;                   // 0..63

  __shared__ __align__(16) float d_s[64];
  __shared__ __align__(16) float k_s[64];

  float Wy[64], Wq[64], Wk[64];
  float wb0, wb1, wb2, wb3;

  {
    const float4* sy4 = reinterpret_cast<const float4*>(st_y + ((size_t)bh*64 + lane)*64);
    const float4* py4 = reinterpret_cast<const float4*>(p_y  + ((size_t)hh*64 + lane)*64);
    const float4* sq4 = reinterpret_cast<const float4*>(st_q + ((size_t)bh*64 + lane)*64);
    const float4* pq4 = reinterpret_cast<const float4*>(p_q  + ((size_t)hh*64 + lane)*64);
    const float4* sk4 = reinterpret_cast<const float4*>(st_k + ((size_t)bh*64 + lane)*64);
    const float4* pk4 = reinterpret_cast<const float4*>(p_k  + ((size_t)hh*64 + lane)*64);
    #pragma unroll
    for (int c=0;c<16;c++){
      float4 a, p;
      a = sy4[c]; p = py4[c];
      Wy[c*4+0]=a.x+p.x; Wy[c*4+1]=a.y+p.y; Wy[c*4+2]=a.z+p.z; Wy[c*4+3]=a.w+p.w;
      a = sq4[c]; p = pq4[c];
      Wq[c*4+0]=a.x+p.x; Wq[c*4+1]=a.y+p.y; Wq[c*4+2]=a.z+p.z; Wq[c*4+3]=a.w+p.w;
      a = sk4[c]; p = pk4[c];
      Wk[c*4+0]=a.x+p.x; Wk[c*4+1]=a.y+p.y; Wk[c*4+2]=a.z+p.z; Wk[c*4+3]=a.w+p.w;
    }
    float4 sv = *reinterpret_cast<const float4*>(st_b + ((size_t)bh*64+lane)*4);
    float4 pv = *reinterpret_cast<const float4*>(p_b  + ((size_t)hh*64+lane)*4);
    wb0 = sv.x+pv.x; wb1 = sv.y+pv.y; wb2 = sv.z+pv.z; wb3 = sv.w+pv.w;
  }

  const float* xbase = xs + (size_t)bh * (S_SEQ*D_DIM);
  float xcur = xbase[lane];

  for (int t=0; t<S_SEQ; ++t){
    const float4* xr4 = reinterpret_cast<const float4*>(xbase + t*D_DIM); // uniform
    float xnext = (t+1<S_SEQ) ? xbase[(t+1)*D_DIM + lane] : 0.f;

    // ---- matvecs with x: ry, rq, rk (3 x 64 FMA, interleaved chains) ----
    float accy[4] = {0.f,0.f,0.f,0.f};
    float accq[4] = {0.f,0.f,0.f,0.f};
    float acck[4] = {0.f,0.f,0.f,0.f};
    #pragma unroll
    for (int j=0;j<16;j++){
      float4 xv = xr4[j];
      const float xa[4] = {xv.x, xv.y, xv.z, xv.w};
      #pragma unroll
      for (int c=0;c<4;c++){
        accy[c] = fmaf(Wy[j*4+c], xa[c], accy[c]);
        accq[c] = fmaf(Wq[j*4+c], xa[c], accq[c]);
        acck[c] = fmaf(Wk[j*4+c], xa[c], acck[c]);
      }
    }
    float ry = (accy[0]+accy[1])+(accy[2]+accy[3]);
    float rq = (accq[0]+accq[1])+(accq[2]+accq[3]);
    float rk = (acck[0]+acck[1])+(acck[2]+acck[3]);

    y_out[((size_t)t*B_NUM + b)*HID_D + hh*D_DIM + lane] = ry;  // pre-update y

    // ---- interleaved butterflies: max(rq), max(rk), sum(beta partials) ----
    float p0 = wb0*xcur, p1 = wb1*xcur, p2 = wb2*xcur, p3 = wb3*xcur;
    float mq = rq, mk = rk;
    #pragma unroll
    for (int off=32; off; off>>=1){
      mq = fmaxf(mq, __shfl_xor(mq,off));
      mk = fmaxf(mk, __shfl_xor(mk,off));
      p0 += __shfl_xor(p0,off);
      p1 += __shfl_xor(p1,off);
      p2 += __shfl_xor(p2,off);
      p3 += __shfl_xor(p3,off);
    }
    float eq = __expf(rq-mq), ek = __expf(rk-mk);
    float sq = eq, sk = ek;
    #pragma unroll
    for (int off=32; off; off>>=1){
      sq += __shfl_xor(sq,off);
      sk += __shfl_xor(sk,off);
    }
    float qn = eq * __builtin_amdgcn_rcpf(sq);
    float kn = ek * __builtin_amdgcn_rcpf(sk);
    float dv = qn - kn;
    d_s[lane] = dv;
    k_s[lane] = kn;

    float b0 = __builtin_amdgcn_rcpf(1.f+__expf(-p0));
    float b1 = __builtin_amdgcn_rcpf(1.f+__expf(-p1));
    float b2 = __builtin_amdgcn_rcpf(1.f+__expf(-p2));
    float b3 = __builtin_amdgcn_rcpf(1.f+__expf(-p3));

    // ---- matvecs with d (pre-update W) ----
    float dcy[4] = {0.f,0.f,0.f,0.f};
    float dcq[4] = {0.f,0.f,0.f,0.f};
    float dck[4] = {0.f,0.f,0.f,0.f};
    #pragma unroll
    for (int j=0;j<16;j++){
      float4 dvv = reinterpret_cast<const float4*>(d_s)[j];
      const float da[4] = {dvv.x, dvv.y, dvv.z, dvv.w};
      #pragma unroll
      for (int c=0;c<4;c++){
        dcy[c] = fmaf(Wy[j*4+c], da[c], dcy[c]);
        dcq[c] = fmaf(Wq[j*4+c], da[c], dcq[c]);
        dck[c] = fmaf(Wk[j*4+c], da[c], dck[c]);
      }
    }
    float dy = (dcy[0]+dcy[1])+(dcy[2]+dcy[3]);
    float dq = (dcq[0]+dcq[1])+(dcq[2]+dcq[3]);
    float dk = (dck[0]+dck[1])+(dck[2]+dck[3]);

    // ---- db reduces (wb pre-update) ----
    float q0 = wb0*dv, q1 = wb1*dv, q2 = wb2*dv, q3 = wb3*dv;
    #pragma unroll
    for (int off=32; off; off>>=1){
      q0 += __shfl_xor(q0,off);
      q1 += __shfl_xor(q1,off);
      q2 += __shfl_xor(q2,off);
      q3 += __shfl_xor(q3,off);
    }

    // ---- rank-1 updates ----
    float ccy = b0*dy, ccq = b1*dq, cck = b2*dk;
    #pragma unroll
    for (int j=0;j<16;j++){
      float4 kv = reinterpret_cast<const float4*>(k_s)[j];
      const float ka[4] = {kv.x, kv.y, kv.z, kv.w};
      #pragma unroll
      for (int c=0;c<4;c++){
        Wy[j*4+c] = fmaf(ccy, ka[c], Wy[j*4+c]);
        Wq[j*4+c] = fmaf(ccq, ka[c], Wq[j*4+c]);
        Wk[j*4+c] = fmaf(cck, ka[c], Wk[j*4+c]);
      }
    }
    float bk = b3*kn;
    wb0 = fmaf(bk, q0, wb0);
    wb1 = fmaf(bk, q1, wb1);
    wb2 = fmaf(bk, q2, wb2);
    wb3 = fmaf(bk, q3, wb3);

    xcur = xnext;
  }

  // ---- final states: (W_final - p) ----
  {
    const float4* py4 = reinterpret_cast<const float4*>(p_y + ((size_t)hh*64 + lane)*64);
    const float4* pq4 = reinterpret_cast<const float4*>(p_q + ((size_t)hh*64 + lane)*64);
    const float4* pk4 = reinterpret_cast<const float4*>(p_k + ((size_t)hh*64 + lane)*64);
    float4* oy = reinterpret_cast<float4*>(o_sy + ((size_t)bh*64 + lane)*64);
    float4* oq = reinterpret_cast<float4*>(o_sq + ((size_t)bh*64 + lane)*64);
    float4* ok = reinterpret_cast<float4*>(o_sk + ((size_t)bh*64 + lane)*64);
    #pragma unroll
    for (int c=0;c<16;c++){
      float4 p, w;
      p = py4[c];
      w.x=Wy[c*4+0]-p.x; w.y=Wy[c*4+1]-p.y; w.z=Wy[c*4+2]-p.z; w.w=Wy[c*4+3]-p.w;
      oy[c] = w;
      p = pq4[c];
      w.x=Wq[c*4+0]-p.x; w.y=Wq[c*4+1]-p.y; w.z=Wq[c*4+2]-p.z; w.w=Wq[c*4+3]-p.w;
      oq[c] = w;
      p = pk4[c];
      w.x=Wk[c*4+0]-p.x; w.y=Wk[c*4+1]-p.y; w.z=Wk[c*4+2]-p.z; w.w=Wk[c*4+3]-p.w;
      ok[c] = w;
    }
    float4 pv = *reinterpret_cast<const float4*>(p_b + ((size_t)hh*64+lane)*4);
    float4 w;
    w.x = wb0-pv.x; w.y = wb1-pv.y; w.z = wb2-pv.z; w.w = wb3-pv.w;
    *reinterpret_cast<float4*>(o_sb + ((size_t)bh*64+lane)*4) = w;
  }
}

// ---------------------------------------------------------------------------
// Vector f32 GEMM: C[m][n] = sum_k A[m][k]*B[n][k] (+bias)(+Cin)(relu)
// A: [M][K] f32 row-major, Bw: [N][K] f32 row-major.
// ---------------------------------------------------------------------------
template<int BM,int BN,int TM,int TN,bool BIAS,bool RELU,bool ADDC>
__global__ __launch_bounds__(256) void gemm_k(
    const float* __restrict__ A, const float* __restrict__ Bw,
    const float* __restrict__ Cin, const float* __restrict__ bias,
    float* __restrict__ Of,
    int M, int N, int K)
{
  constexpr int BK = 16;
  constexpr int TX = BN/TN;
  constexpr int TY = BM/TM;
  static_assert(TX*TY==256, "bad tiling");
  __shared__ __align__(16) float As[BK][BM];
  __shared__ __align__(16) float Bs[BK][BN];
  const int tid = threadIdx.x;
  const int tx = tid % TX;
  const int ty = tid / TX;
  const int m0 = blockIdx.y*BM, n0 = blockIdx.x*BN;
  float acc[TM][TN] = {};

  for (int k0=0; k0<K; k0+=BK){
    { // stage A (BM rows x BK cols, transposed into As[k][m])
      constexpr int E = BM*BK/256;       // elems per thread (8 or 4)
      constexpr int TPR = BK/E;          // threads per row
      int r  = tid / TPR;
      int kk = (tid % TPR) * E;
      const float* src = A + (size_t)(m0+r)*K + k0 + kk;
      #pragma unroll
      for (int c=0;c<E;c+=4){
        float4 v = *reinterpret_cast<const float4*>(src + c);
        As[kk+c+0][r]=v.x; As[kk+c+1][r]=v.y; As[kk+c+2][r]=v.z; As[kk+c+3][r]=v.w;
      }
    }
    { // stage B
      constexpr int E = BN*BK/256;
      constexpr int TPR = BK/E;
      int r  = tid / TPR;
      int kk = (tid % TPR) * E;
      const float* src = Bw + (size_t)(n0+r)*K + k0 + kk;
      #pragma unroll
      for (int c=0;c<E;c+=4){
        float4 v = *reinterpret_cast<const float4*>(src + c);
        Bs[kk+c+0][r]=v.x; Bs[kk+c+1][r]=v.y; Bs[kk+c+2][r]=v.z; Bs[kk+c+3][r]=v.w;
      }
    }
    __syncthreads();
    #pragma unroll
    for (int kk=0;kk<BK;kk++){
      float a[TM], bf[TN];
      #pragma unroll
      for (int i=0;i<TM;i++) a[i] = As[kk][ty*TM+i];
      #pragma unroll
      for (int j=0;j<TN;j++) bf[j] = Bs[kk][tx*TN+j];
      #pragma unroll
      for (int i=0;i<TM;i++)
        #pragma unroll
        for (int j=0;j<TN;j++)
          acc[i][j] = fmaf(a[i], bf[j], acc[i][j]);
    }
    __syncthreads();
  }

  #pragma unroll
  for (int i=0;i<TM;i++){
    int row = m0 + ty*TM + i;
    #pragma unroll
    for (int j0=0;j0<TN;j0+=4){
      int col = n0 + tx*TN + j0;
      float4 v = make_float4(acc[i][j0],acc[i][j0+1],acc[i][j0+2],acc[i][j0+3]);
      if (BIAS){
        float4 bv = *reinterpret_cast<const float4*>(bias+col);
        v.x += bv.x; v.y += bv.y; v.z += bv.z; v.w += bv.w;
      }
      if (ADDC){
        float4 c = *reinterpret_cast<const float4*>(Cin + (size_t)row*N + col);
        v.x+=c.x; v.y+=c.y; v.z+=c.z; v.w+=c.w;
      }
      if (RELU){
        v.x=fmaxf(v.x,0.f); v.y=fmaxf(v.y,0.f); v.z=fmaxf(v.z,0.f); v.w=fmaxf(v.w,0.f);
      }
      *reinterpret_cast<float4*>(Of + (size_t)row*N + col) = v;
    }
  }
}

// ---------------------------------------------------------------------------
// LayerNorm over HID=512, wave per row, 8 elems/lane. f32 -> f32.
// ---------------------------------------------------------------------------
__global__ __launch_bounds__(256) void ln_k(
    const float* __restrict__ h, const float* __restrict__ g,
    const float* __restrict__ bb, float* __restrict__ out)
{
  int row  = blockIdx.x*4 + (threadIdx.x>>6);
  int lane = threadIdx.x & 63;
  const float4* hr = reinterpret_cast<const float4*>(h + (size_t)row*HID_D) + lane*2;
  float4 u = hr[0], v = hr[1];
  float vals[8] = {u.x,u.y,u.z,u.w,v.x,v.y,v.z,v.w};
  float s = 0.f;
  #pragma unroll
  for (int e=0;e<8;e++) s += vals[e];
  #pragma unroll
  for (int off=32; off; off>>=1) s += __shfl_xor(s,off);
  float mu = s * (1.f/HID_D);
  float vs = 0.f;
  #pragma unroll
  for (int e=0;e<8;e++){ float d = vals[e]-mu; vs += d*d; }
  #pragma unroll
  for (int off=32; off; off>>=1) vs += __shfl_xor(vs,off);
  float rs = rsqrtf(vs*(1.f/HID_D) + 1e-5f);
  const float4* gr = reinterpret_cast<const float4*>(g) + lane*2;
  const float4* br = reinterpret_cast<const float4*>(bb) + lane*2;
  float4 g0 = gr[0], g1 = gr[1], b0 = br[0], b1 = br[1];
  float4 o0, o1;
  o0.x = (vals[0]-mu)*rs*g0.x + b0.x;
  o0.y = (vals[1]-mu)*rs*g0.y + b0.y;
  o0.z = (vals[2]-mu)*rs*g0.z + b0.z;
  o0.w = (vals[3]-mu)*rs*g0.w + b0.w;
  o1.x = (vals[4]-mu)*rs*g1.x + b1.x;
  o1.y = (vals[5]-mu)*rs*g1.y + b1.y;
  o1.z = (vals[6]-mu)*rs*g1.z + b1.z;
  o1.w = (vals[7]-mu)*rs*g1.w + b1.w;
  float4* orow = reinterpret_cast<float4*>(out + (size_t)row*HID_D) + lane*2;
  orow[0] = o0; orow[1] = o1;
}

// ---------------------------------------------------------------------------
extern "C" void kernel_launch(void* const* d_in, const int* in_sizes, int n_in,
                              void* d_out, int out_size, void* d_ws, size_t ws_size,
                              hipStream_t stream)
{
  const float* x    = (const float*)d_in[0];
  const float* sty  = (const float*)d_in[1];
  const float* stq  = (const float*)d_in[2];
  const float* stk  = (const float*)d_in[3];
  const float* stb  = (const float*)d_in[4];
  const float* inW  = (const float*)d_in[5];
  const float* inb  = (const float*)d_in[6];
  const float* py   = (const float*)d_in[7];
  const float* pq   = (const float*)d_in[8];
  const float* pk   = (const float*)d_in[9];
  const float* pb   = (const float*)d_in[10];
  const float* Wo   = (const float*)d_in[11];
  const float* fw1  = (const float*)d_in[12];
  const float* fb1  = (const float*)d_in[13];
  const float* fw2  = (const float*)d_in[14];
  const float* fb2  = (const float*)d_in[15];
  const float* lng  = (const float*)d_in[16];
  const float* lnb  = (const float*)d_in[17];

  char* ws = (char*)d_ws;
  float* h   = (float*)ws;                  // 4 MB (2048 x 512)
  float* xsb = (float*)(ws + (4<<20));      // 4 MB (B,H,S,D)
  float* yb  = (float*)(ws + (8<<20));      // 4 MB (S,B,HID)
  float* t0  = (float*)(ws + (12<<20));     // 4 MB (ln out)
  float* t1  = (float*)(ws + (16<<20));     // 16 MB (2048 x 2048)

  float* out0 = (float*)d_out;
  const size_t OUT_SZ = (size_t)S_SEQ*B_NUM*HID_D;          // 1048576
  const size_t SYL    = (size_t)B_NUM*H_NUM*D_DIM*D_DIM;    // 262144 per layer
  const size_t SBL    = (size_t)B_NUM*H_NUM*D_DIM*4;        // 16384  per layer
  float* o_sy = out0 + OUT_SZ;
  float* o_sq = o_sy + L_NUM*SYL;
  float* o_sk = o_sq + L_NUM*SYL;
  float* o_sb = o_sk + L_NUM*SYL;

  const int M = S_SEQ*B_NUM;   // 2048
  dim3 gN512(HID_D/64, M/128); // (8,16)

  // in-projection: h = x @ in_W.T + in_b
  gemm_k<128,64,8,4,true,false,false><<<gN512,256,0,stream>>>(
      x, inW, nullptr, inb, h, M, HID_D, 512);

  for (int l=0;l<L_NUM;l++){
    softmax_xs_k<<<(S_SEQ*B_NUM*H_NUM)/4, 256, 0, stream>>>(h, xsb);

    scan1_k<<<B_NUM*H_NUM, 64, 0, stream>>>(xsb,
        sty + (size_t)l*SYL, stq + (size_t)l*SYL, stk + (size_t)l*SYL, stb + (size_t)l*SBL,
        py + (size_t)l*H_NUM*D_DIM*D_DIM, pq + (size_t)l*H_NUM*D_DIM*D_DIM,
        pk + (size_t)l*H_NUM*D_DIM*D_DIM, pb + (size_t)l*H_NUM*D_DIM*4,
        yb,
        o_sy + l*SYL, o_sq + l*SYL, o_sk + l*SYL, o_sb + l*SBL);

    // h += y @ Wo.T
    gemm_k<128,64,8,4,false,false,true><<<gN512,256,0,stream>>>(
        yb, Wo + (size_t)l*HID_D*HID_D, h, nullptr, h, M, HID_D, HID_D);

    ln_k<<<M/4,256,0,stream>>>(h, lng + l*HID_D, lnb + l*HID_D, t0);

    // t1 = relu(ln @ ff_W1.T + b1)
    gemm_k<128,128,8,8,true,true,false><<<dim3(FF_D/128, M/128),256,0,stream>>>(
        t0, fw1 + (size_t)l*FF_D*HID_D, nullptr, fb1 + l*FF_D, t1, M, FF_D, HID_D);

    // h(+out) = h + t1 @ ff_W2.T + b2   (last layer writes d_out directly)
    float* dst = (l==L_NUM-1) ? out0 : h;
    gemm_k<128,64,8,4,true,false,true><<<gN512,256,0,stream>>>(
        t1, fw2 + (size_t)l*HID_D*FF_D, h, fb2 + l*HID_D, dst, M, HID_D, FF_D);
  }
}

// Round 4
// 1349.826 us; speedup vs baseline: 1.8840x; 1.8840x over previous
//
#include <hip/hip_runtime.h>

#define L_NUM 2
#define H_NUM 8
#define D_DIM 64
#define HID_D 512
#define FF_D  2048
#define S_SEQ 256
#define B_NUM 8

// ---------------------------------------------------------------------------
// Per-head softmax: h (S,B,HID) f32 -> xs (B,H,S,D) f32. One wave per 64-row.
// ---------------------------------------------------------------------------
__global__ __launch_bounds__(256) void softmax_xs_k(
    const float* __restrict__ h, float* __restrict__ xs)
{
  int rid  = blockIdx.x*4 + (threadIdx.x>>6);   // (s*B+b)*H + hd
  int lane = threadIdx.x & 63;
  int hd = rid & (H_NUM-1);
  int sb = rid >> 3;                            // s*B + b
  int b  = sb & (B_NUM-1);
  int s  = sb >> 3;
  float v = h[(size_t)sb*HID_D + hd*D_DIM + lane];
  float m = v;
  #pragma unroll
  for (int off=32; off; off>>=1) m = fmaxf(m, __shfl_xor(m, off));
  float e = __expf(v-m);
  float sum = e;
  #pragma unroll
  for (int off=32; off; off>>=1) sum += __shfl_xor(sum, off);
  xs[(((size_t)(b*H_NUM+hd))*S_SEQ + s)*D_DIM + lane] = e/sum;
}

// ---------------------------------------------------------------------------
// SRWM scan, 4 waves per (b,h): wave0 Wy, wave1 Wq, wave2 Wk, wave3 wb.
// Critical-path optimized: x-row register-prefetch (1 step ahead),
// double-buffered q/k/beta -> ONE barrier per step, no max-subtract.
// ---------------------------------------------------------------------------
__global__ __launch_bounds__(256,1) void scan4_k(
    const float* __restrict__ xs,                 // (B,H,S,D) f32
    const float* __restrict__ st_y, const float* __restrict__ st_q,
    const float* __restrict__ st_k, const float* __restrict__ st_b,
    const float* __restrict__ p_y,  const float* __restrict__ p_q,
    const float* __restrict__ p_k,  const float* __restrict__ p_b,
    float* __restrict__ y_out,                    // (S,B,HID) f32
    float* __restrict__ o_sy, float* __restrict__ o_sq,
    float* __restrict__ o_sk, float* __restrict__ o_sb)
{
  const int bh = blockIdx.x;
  const int b  = bh >> 3, hh = bh & 7;
  const int wave = threadIdx.x >> 6, lane = threadIdx.x & 63;

  __shared__ __align__(16) float q_s[2][64];
  __shared__ __align__(16) float k_s[2][64];
  __shared__ float beta_s[2][4];

  float W[64];                                   // waves 0-2: row `lane`
  float wb0=0.f, wb1=0.f, wb2=0.f, wb3=0.f;      // wave 3

  if (wave < 3) {
    const float* st = (wave==0)? st_y : (wave==1)? st_q : st_k;
    const float* pp = (wave==0)? p_y  : (wave==1)? p_q  : p_k;
    const float4* s4 = reinterpret_cast<const float4*>(st + ((size_t)bh*64 + lane)*64);
    const float4* p4 = reinterpret_cast<const float4*>(pp + ((size_t)hh*64 + lane)*64);
    #pragma unroll
    for (int c=0;c<16;c++){
      float4 a = s4[c], p = p4[c];
      W[c*4+0]=a.x+p.x; W[c*4+1]=a.y+p.y; W[c*4+2]=a.z+p.z; W[c*4+3]=a.w+p.w;
    }
  } else {
    float4 sv = *reinterpret_cast<const float4*>(st_b + ((size_t)bh*64+lane)*4);
    float4 pv = *reinterpret_cast<const float4*>(p_b  + ((size_t)hh*64+lane)*4);
    wb0 = sv.x+pv.x; wb1 = sv.y+pv.y; wb2 = sv.z+pv.z; wb3 = sv.w+pv.w;
  }

  const float* xbase = xs + (size_t)bh * (S_SEQ*D_DIM);

  float xA[64], xB[64];                          // full x row (uniform) dbl-buf
  float xl_cur, xl_nxt;                          // per-lane x element (wave3)
  {
    const float4* xr4 = reinterpret_cast<const float4*>(xbase);
    #pragma unroll
    for (int j=0;j<16;j++){
      float4 v = xr4[j];
      xA[j*4+0]=v.x; xA[j*4+1]=v.y; xA[j*4+2]=v.z; xA[j*4+3]=v.w;
    }
    xl_cur = xbase[lane];
  }

#define SRWM_STEP(T, XC, XN, BUF) do {                                         \
    const int tn_ = ((T)+1) & (S_SEQ-1);                                       \
    { /* prefetch next x row + next per-lane element (off critical path) */    \
      const float4* xr4_ = reinterpret_cast<const float4*>(xbase + tn_*D_DIM); \
      _Pragma("unroll")                                                        \
      for (int j=0;j<16;j++){                                                  \
        float4 v_ = xr4_[j];                                                   \
        XN[j*4+0]=v_.x; XN[j*4+1]=v_.y; XN[j*4+2]=v_.z; XN[j*4+3]=v_.w;        \
      }                                                                        \
      xl_nxt = xbase[tn_*D_DIM + lane];                                        \
    }                                                                          \
    if (wave < 3){                                                             \
      float a0=0.f,a1=0.f,a2=0.f,a3=0.f;                                       \
      _Pragma("unroll")                                                        \
      for (int j=0;j<64;j+=4){                                                 \
        a0 = fmaf(W[j+0], XC[j+0], a0);                                        \
        a1 = fmaf(W[j+1], XC[j+1], a1);                                        \
        a2 = fmaf(W[j+2], XC[j+2], a2);                                        \
        a3 = fmaf(W[j+3], XC[j+3], a3);                                        \
      }                                                                        \
      float r = (a0+a1)+(a2+a3);                                               \
      if (wave==0){                                                            \
        y_out[((size_t)(T)*B_NUM + b)*HID_D + hh*D_DIM + lane] = r;            \
      } else {                                                                 \
        float e = __expf(r);                                                   \
        float s = e;                                                           \
        _Pragma("unroll")                                                      \
        for (int off=32; off; off>>=1) s += __shfl_xor(s,off);                 \
        float val = e * __builtin_amdgcn_rcpf(s);                              \
        (wave==1 ? q_s[BUF] : k_s[BUF])[lane] = val;                           \
      }                                                                        \
    } else {                                                                   \
      float p0 = wb0*xl_cur, p1 = wb1*xl_cur, p2 = wb2*xl_cur, p3 = wb3*xl_cur;\
      _Pragma("unroll")                                                        \
      for (int off=32; off; off>>=1){                                          \
        p0 += __shfl_xor(p0,off); p1 += __shfl_xor(p1,off);                    \
        p2 += __shfl_xor(p2,off); p3 += __shfl_xor(p3,off);                    \
      }                                                                        \
      if (lane==0){                                                            \
        beta_s[BUF][0] = __builtin_amdgcn_rcpf(1.f+__expf(-p0));               \
        beta_s[BUF][1] = __builtin_amdgcn_rcpf(1.f+__expf(-p1));               \
        beta_s[BUF][2] = __builtin_amdgcn_rcpf(1.f+__expf(-p2));               \
        beta_s[BUF][3] = __builtin_amdgcn_rcpf(1.f+__expf(-p3));               \
      }                                                                        \
    }                                                                          \
    __syncthreads();                                                           \
    if (wave < 3){                                                             \
      float bw = beta_s[BUF][wave];                                            \
      float a0=0.f,a1=0.f,a2=0.f,a3=0.f;                                       \
      _Pragma("unroll")                                                        \
      for (int j=0;j<16;j++){                                                  \
        float4 qv = reinterpret_cast<const float4*>(q_s[BUF])[j];              \
        float4 kv = reinterpret_cast<const float4*>(k_s[BUF])[j];              \
        a0 = fmaf(W[j*4+0], qv.x-kv.x, a0);                                    \
        a1 = fmaf(W[j*4+1], qv.y-kv.y, a1);                                    \
        a2 = fmaf(W[j*4+2], qv.z-kv.z, a2);                                    \
        a3 = fmaf(W[j*4+3], qv.w-kv.w, a3);                                    \
      }                                                                        \
      float rd = (a0+a1)+(a2+a3);                                              \
      float cc = bw * rd;                                                      \
      _Pragma("unroll")                                                        \
      for (int j=0;j<16;j++){                                                  \
        float4 kv = reinterpret_cast<const float4*>(k_s[BUF])[j];              \
        W[j*4+0] = fmaf(cc, kv.x, W[j*4+0]);                                   \
        W[j*4+1] = fmaf(cc, kv.y, W[j*4+1]);                                   \
        W[j*4+2] = fmaf(cc, kv.z, W[j*4+2]);                                   \
        W[j*4+3] = fmaf(cc, kv.w, W[j*4+3]);                                   \
      }                                                                        \
    } else {                                                                   \
      float qn = q_s[BUF][lane], kn = k_s[BUF][lane];                          \
      float dv = qn - kn;                                                      \
      float d0 = wb0*dv, d1 = wb1*dv, d2 = wb2*dv, d3 = wb3*dv;                \
      _Pragma("unroll")                                                        \
      for (int off=32; off; off>>=1){                                          \
        d0 += __shfl_xor(d0,off); d1 += __shfl_xor(d1,off);                    \
        d2 += __shfl_xor(d2,off); d3 += __shfl_xor(d3,off);                    \
      }                                                                        \
      float bk = beta_s[BUF][3] * kn;                                          \
      wb0 = fmaf(bk, d0, wb0);                                                 \
      wb1 = fmaf(bk, d1, wb1);                                                 \
      wb2 = fmaf(bk, d2, wb2);                                                 \
      wb3 = fmaf(bk, d3, wb3);                                                 \
    }                                                                          \
    xl_cur = xl_nxt;                                                           \
  } while(0)

  for (int t=0; t<S_SEQ; t+=2){
    SRWM_STEP(t,   xA, xB, 0);
    SRWM_STEP(t+1, xB, xA, 1);
  }
#undef SRWM_STEP

  // ---- final states: (W_final - p) ----
  if (wave < 3){
    const float* pp = (wave==0)? p_y : (wave==1)? p_q : p_k;
    float* o = ((wave==0)? o_sy : (wave==1)? o_sq : o_sk) + ((size_t)bh*64 + lane)*64;
    const float4* p4 = reinterpret_cast<const float4*>(pp + ((size_t)hh*64 + lane)*64);
    #pragma unroll
    for (int c=0;c<16;c++){
      float4 p = p4[c];
      float4 w;
      w.x = W[c*4+0]-p.x; w.y = W[c*4+1]-p.y; w.z = W[c*4+2]-p.z; w.w = W[c*4+3]-p.w;
      reinterpret_cast<float4*>(o)[c] = w;
    }
  } else {
    float4 pv = *reinterpret_cast<const float4*>(p_b + ((size_t)hh*64+lane)*4);
    float4 w;
    w.x = wb0-pv.x; w.y = wb1-pv.y; w.z = wb2-pv.z; w.w = wb3-pv.w;
    *reinterpret_cast<float4*>(o_sb + ((size_t)bh*64+lane)*4) = w;
  }
}

// ---------------------------------------------------------------------------
// Vector f32 GEMM: C[m][n] = sum_k A[m][k]*B[n][k] (+bias)(+Cin)(relu)
// A: [M][K] f32 row-major, Bw: [N][K] f32 row-major.
// ---------------------------------------------------------------------------
template<int BM,int BN,int TM,int TN,bool BIAS,bool RELU,bool ADDC>
__global__ __launch_bounds__(256) void gemm_k(
    const float* __restrict__ A, const float* __restrict__ Bw,
    const float* __restrict__ Cin, const float* __restrict__ bias,
    float* __restrict__ Of,
    int M, int N, int K)
{
  constexpr int BK = 16;
  constexpr int TX = BN/TN;
  constexpr int TY = BM/TM;
  static_assert(TX*TY==256, "bad tiling");
  __shared__ __align__(16) float As[BK][BM];
  __shared__ __align__(16) float Bs[BK][BN];
  const int tid = threadIdx.x;
  const int tx = tid % TX;
  const int ty = tid / TX;
  const int m0 = blockIdx.y*BM, n0 = blockIdx.x*BN;
  float acc[TM][TN] = {};

  for (int k0=0; k0<K; k0+=BK){
    { // stage A (BM rows x BK cols, transposed into As[k][m])
      constexpr int E = BM*BK/256;       // elems per thread (8 or 4)
      constexpr int TPR = BK/E;          // threads per row
      int r  = tid / TPR;
      int kk = (tid % TPR) * E;
      const float* src = A + (size_t)(m0+r)*K + k0 + kk;
      #pragma unroll
      for (int c=0;c<E;c+=4){
        float4 v = *reinterpret_cast<const float4*>(src + c);
        As[kk+c+0][r]=v.x; As[kk+c+1][r]=v.y; As[kk+c+2][r]=v.z; As[kk+c+3][r]=v.w;
      }
    }
    { // stage B
      constexpr int E = BN*BK/256;
      constexpr int TPR = BK/E;
      int r  = tid / TPR;
      int kk = (tid % TPR) * E;
      const float* src = Bw + (size_t)(n0+r)*K + k0 + kk;
      #pragma unroll
      for (int c=0;c<E;c+=4){
        float4 v = *reinterpret_cast<const float4*>(src + c);
        Bs[kk+c+0][r]=v.x; Bs[kk+c+1][r]=v.y; Bs[kk+c+2][r]=v.z; Bs[kk+c+3][r]=v.w;
      }
    }
    __syncthreads();
    #pragma unroll
    for (int kk=0;kk<BK;kk++){
      float a[TM], bf[TN];
      #pragma unroll
      for (int i=0;i<TM;i++) a[i] = As[kk][ty*TM+i];
      #pragma unroll
      for (int j=0;j<TN;j++) bf[j] = Bs[kk][tx*TN+j];
      #pragma unroll
      for (int i=0;i<TM;i++)
        #pragma unroll
        for (int j=0;j<TN;j++)
          acc[i][j] = fmaf(a[i], bf[j], acc[i][j]);
    }
    __syncthreads();
  }

  #pragma unroll
  for (int i=0;i<TM;i++){
    int row = m0 + ty*TM + i;
    #pragma unroll
    for (int j0=0;j0<TN;j0+=4){
      int col = n0 + tx*TN + j0;
      float4 v = make_float4(acc[i][j0],acc[i][j0+1],acc[i][j0+2],acc[i][j0+3]);
      if (BIAS){
        float4 bv = *reinterpret_cast<const float4*>(bias+col);
        v.x += bv.x; v.y += bv.y; v.z += bv.z; v.w += bv.w;
      }
      if (ADDC){
        float4 c = *reinterpret_cast<const float4*>(Cin + (size_t)row*N + col);
        v.x+=c.x; v.y+=c.y; v.z+=c.z; v.w+=c.w;
      }
      if (RELU){
        v.x=fmaxf(v.x,0.f); v.y=fmaxf(v.y,0.f); v.z=fmaxf(v.z,0.f); v.w=fmaxf(v.w,0.f);
      }
      *reinterpret_cast<float4*>(Of + (size_t)row*N + col) = v;
    }
  }
}

// ---------------------------------------------------------------------------
// LayerNorm over HID=512, wave per row, 8 elems/lane. f32 -> f32.
// ---------------------------------------------------------------------------
__global__ __launch_bounds__(256) void ln_k(
    const float* __restrict__ h, const float* __restrict__ g,
    const float* __restrict__ bb, float* __restrict__ out)
{
  int row  = blockIdx.x*4 + (threadIdx.x>>6);
  int lane = threadIdx.x & 63;
  const float4* hr = reinterpret_cast<const float4*>(h + (size_t)row*HID_D) + lane*2;
  float4 u = hr[0], v = hr[1];
  float vals[8] = {u.x,u.y,u.z,u.w,v.x,v.y,v.z,v.w};
  float s = 0.f;
  #pragma unroll
  for (int e=0;e<8;e++) s += vals[e];
  #pragma unroll
  for (int off=32; off; off>>=1) s += __shfl_xor(s,off);
  float mu = s * (1.f/HID_D);
  float vs = 0.f;
  #pragma unroll
  for (int e=0;e<8;e++){ float d = vals[e]-mu; vs += d*d; }
  #pragma unroll
  for (int off=32; off; off>>=1) vs += __shfl_xor(vs,off);
  float rs = rsqrtf(vs*(1.f/HID_D) + 1e-5f);
  const float4* gr = reinterpret_cast<const float4*>(g) + lane*2;
  const float4* br = reinterpret_cast<const float4*>(bb) + lane*2;
  float4 g0 = gr[0], g1 = gr[1], b0 = br[0], b1 = br[1];
  float4 o0, o1;
  o0.x = (vals[0]-mu)*rs*g0.x + b0.x;
  o0.y = (vals[1]-mu)*rs*g0.y + b0.y;
  o0.z = (vals[2]-mu)*rs*g0.z + b0.z;
  o0.w = (vals[3]-mu)*rs*g0.w + b0.w;
  o1.x = (vals[4]-mu)*rs*g1.x + b1.x;
  o1.y = (vals[5]-mu)*rs*g1.y + b1.y;
  o1.z = (vals[6]-mu)*rs*g1.z + b1.z;
  o1.w = (vals[7]-mu)*rs*g1.w + b1.w;
  float4* orow = reinterpret_cast<float4*>(out + (size_t)row*HID_D) + lane*2;
  orow[0] = o0; orow[1] = o1;
}

// ---------------------------------------------------------------------------
extern "C" void kernel_launch(void* const* d_in, const int* in_sizes, int n_in,
                              void* d_out, int out_size, void* d_ws, size_t ws_size,
                              hipStream_t stream)
{
  const float* x    = (const float*)d_in[0];
  const float* sty  = (const float*)d_in[1];
  const float* stq  = (const float*)d_in[2];
  const float* stk  = (const float*)d_in[3];
  const float* stb  = (const float*)d_in[4];
  const float* inW  = (const float*)d_in[5];
  const float* inb  = (const float*)d_in[6];
  const float* py   = (const float*)d_in[7];
  const float* pq   = (const float*)d_in[8];
  const float* pk   = (const float*)d_in[9];
  const float* pb   = (const float*)d_in[10];
  const float* Wo   = (const float*)d_in[11];
  const float* fw1  = (const float*)d_in[12];
  const float* fb1  = (const float*)d_in[13];
  const float* fw2  = (const float*)d_in[14];
  const float* fb2  = (const float*)d_in[15];
  const float* lng  = (const float*)d_in[16];
  const float* lnb  = (const float*)d_in[17];

  char* ws = (char*)d_ws;
  float* h   = (float*)ws;                  // 4 MB (2048 x 512)
  float* xsb = (float*)(ws + (4<<20));      // 4 MB (B,H,S,D)
  float* yb  = (float*)(ws + (8<<20));      // 4 MB (S,B,HID)
  float* t0  = (float*)(ws + (12<<20));     // 4 MB (ln out)
  float* t1  = (float*)(ws + (16<<20));     // 16 MB (2048 x 2048)

  float* out0 = (float*)d_out;
  const size_t OUT_SZ = (size_t)S_SEQ*B_NUM*HID_D;          // 1048576
  const size_t SYL    = (size_t)B_NUM*H_NUM*D_DIM*D_DIM;    // 262144 per layer
  const size_t SBL    = (size_t)B_NUM*H_NUM*D_DIM*4;        // 16384  per layer
  float* o_sy = out0 + OUT_SZ;
  float* o_sq = o_sy + L_NUM*SYL;
  float* o_sk = o_sq + L_NUM*SYL;
  float* o_sb = o_sk + L_NUM*SYL;

  const int M = S_SEQ*B_NUM;   // 2048
  dim3 gN512(HID_D/64, M/128); // (8,16)

  // in-projection: h = x @ in_W.T + in_b
  gemm_k<128,64,8,4,true,false,false><<<gN512,256,0,stream>>>(
      x, inW, nullptr, inb, h, M, HID_D, 512);

  for (int l=0;l<L_NUM;l++){
    softmax_xs_k<<<(S_SEQ*B_NUM*H_NUM)/4, 256, 0, stream>>>(h, xsb);

    scan4_k<<<B_NUM*H_NUM, 256, 0, stream>>>(xsb,
        sty + (size_t)l*SYL, stq + (size_t)l*SYL, stk + (size_t)l*SYL, stb + (size_t)l*SBL,
        py + (size_t)l*H_NUM*D_DIM*D_DIM, pq + (size_t)l*H_NUM*D_DIM*D_DIM,
        pk + (size_t)l*H_NUM*D_DIM*D_DIM, pb + (size_t)l*H_NUM*D_DIM*4,
        yb,
        o_sy + l*SYL, o_sq + l*SYL, o_sk + l*SYL, o_sb + l*SBL);

    // h += y @ Wo.T
    gemm_k<128,64,8,4,false,false,true><<<gN512,256,0,stream>>>(
        yb, Wo + (size_t)l*HID_D*HID_D, h, nullptr, h, M, HID_D, HID_D);

    ln_k<<<M/4,256,0,stream>>>(h, lng + l*HID_D, lnb + l*HID_D, t0);

    // t1 = relu(ln @ ff_W1.T + b1)
    gemm_k<128,128,8,8,true,true,false><<<dim3(FF_D/128, M/128),256,0,stream>>>(
        t0, fw1 + (size_t)l*FF_D*HID_D, nullptr, fb1 + l*FF_D, t1, M, FF_D, HID_D);

    // h(+out) = h + t1 @ ff_W2.T + b2   (last layer writes d_out directly)
    float* dst = (l==L_NUM-1) ? out0 : h;
    gemm_k<128,64,8,4,true,false,true><<<gN512,256,0,stream>>>(
        t1, fw2 + (size_t)l*HID_D*FF_D, h, fb2 + l*HID_D, dst, M, HID_D, FF_D);
  }
}

// Round 5
// 1259.518 us; speedup vs baseline: 2.0191x; 1.0717x over previous
//
#include <hip/hip_runtime.h>

#define L_NUM 2
#define H_NUM 8
#define D_DIM 64
#define HID_D 512
#define FF_D  2048
#define S_SEQ 256
#define B_NUM 8

// ---------------------------------------------------------------------------
// DPP wave64 sum -> uniform (SGPR) result on all lanes.
// row_shr:1/2/4/8 within 16-lane rows, then row_bcast:15 (rows 1,3),
// row_bcast:31 (rows 2,3); total lands in lane 63; readlane broadcasts.
// ---------------------------------------------------------------------------
__device__ __forceinline__ float wave_sum(float v){
  float t;
  t = __int_as_float(__builtin_amdgcn_update_dpp(0, __float_as_int(v), 0x111, 0xf, 0xf, false)); v += t;
  t = __int_as_float(__builtin_amdgcn_update_dpp(0, __float_as_int(v), 0x112, 0xf, 0xf, false)); v += t;
  t = __int_as_float(__builtin_amdgcn_update_dpp(0, __float_as_int(v), 0x114, 0xf, 0xf, false)); v += t;
  t = __int_as_float(__builtin_amdgcn_update_dpp(0, __float_as_int(v), 0x118, 0xf, 0xf, false)); v += t;
  t = __int_as_float(__builtin_amdgcn_update_dpp(0, __float_as_int(v), 0x142, 0xa, 0xf, false)); v += t;
  t = __int_as_float(__builtin_amdgcn_update_dpp(0, __float_as_int(v), 0x143, 0xc, 0xf, false)); v += t;
  return __int_as_float(__builtin_amdgcn_readlane(__float_as_int(v), 63));
}

// ---------------------------------------------------------------------------
// Per-head softmax: h (S,B,HID) f32 -> xs (B,H,S,D) f32. One wave per 64-row.
// ---------------------------------------------------------------------------
__global__ __launch_bounds__(256) void softmax_xs_k(
    const float* __restrict__ h, float* __restrict__ xs)
{
  int rid  = blockIdx.x*4 + (threadIdx.x>>6);   // (s*B+b)*H + hd
  int lane = threadIdx.x & 63;
  int hd = rid & (H_NUM-1);
  int sb = rid >> 3;                            // s*B + b
  int b  = sb & (B_NUM-1);
  int s  = sb >> 3;
  float v = h[(size_t)sb*HID_D + hd*D_DIM + lane];
  float m = v;
  #pragma unroll
  for (int off=32; off; off>>=1) m = fmaxf(m, __shfl_xor(m, off));
  float e = __expf(v-m);
  float sum = wave_sum(e);
  xs[(((size_t)(b*H_NUM+hd))*S_SEQ + s)*D_DIM + lane] = e/sum;
}

// ---------------------------------------------------------------------------
// SRWM scan, 4 waves per (b,h): wave0 Wy, wave1 Wq, wave2 Wk, wave3 wb.
// x staged in LDS (wave3 prefetches 1 step ahead: 1 global load + 1 ds_write),
// DPP reduces (no ds_swizzle chains), 1 barrier/step, dbl-buffered q/k/beta/x.
// ---------------------------------------------------------------------------
__global__ __launch_bounds__(256,1) void scan4_k(
    const float* __restrict__ xs,                 // (B,H,S,D) f32
    const float* __restrict__ st_y, const float* __restrict__ st_q,
    const float* __restrict__ st_k, const float* __restrict__ st_b,
    const float* __restrict__ p_y,  const float* __restrict__ p_q,
    const float* __restrict__ p_k,  const float* __restrict__ p_b,
    float* __restrict__ y_out,                    // (S,B,HID) f32
    float* __restrict__ o_sy, float* __restrict__ o_sq,
    float* __restrict__ o_sk, float* __restrict__ o_sb)
{
  const int bh = blockIdx.x;
  const int b  = bh >> 3, hh = bh & 7;
  const int wave = threadIdx.x >> 6, lane = threadIdx.x & 63;

  __shared__ __align__(16) float q_s[2][64];
  __shared__ __align__(16) float k_s[2][64];
  __shared__ __align__(16) float x_lds[2][64];
  __shared__ float beta_s[2][4];

  float W[64];                                   // waves 0-2: row `lane`
  float wb0=0.f, wb1=0.f, wb2=0.f, wb3=0.f;      // wave 3
  float xl_cur=0.f, xl_nxt=0.f;                  // wave 3 per-lane x element
  float b3_reg=0.f;                              // wave 3 beta[3]

  if (wave < 3) {
    const float* st = (wave==0)? st_y : (wave==1)? st_q : st_k;
    const float* pp = (wave==0)? p_y  : (wave==1)? p_q  : p_k;
    const float4* s4 = reinterpret_cast<const float4*>(st + ((size_t)bh*64 + lane)*64);
    const float4* p4 = reinterpret_cast<const float4*>(pp + ((size_t)hh*64 + lane)*64);
    #pragma unroll
    for (int c=0;c<16;c++){
      float4 a = s4[c], p = p4[c];
      W[c*4+0]=a.x+p.x; W[c*4+1]=a.y+p.y; W[c*4+2]=a.z+p.z; W[c*4+3]=a.w+p.w;
    }
  } else {
    float4 sv = *reinterpret_cast<const float4*>(st_b + ((size_t)bh*64+lane)*4);
    float4 pv = *reinterpret_cast<const float4*>(p_b  + ((size_t)hh*64+lane)*4);
    wb0 = sv.x+pv.x; wb1 = sv.y+pv.y; wb2 = sv.z+pv.z; wb3 = sv.w+pv.w;
  }

  const float* xbase = xs + (size_t)bh * (S_SEQ*D_DIM);
  if (wave == 3){
    xl_cur = xbase[lane];
    x_lds[0][lane] = xl_cur;
  }
  __syncthreads();

  for (int t=0; t<S_SEQ; ++t){
    const int buf = t & 1;
    // ---- phase A ----
    if (wave < 3){
      const float4* xr4 = reinterpret_cast<const float4*>(x_lds[buf]);
      float a0=0.f,a1=0.f,a2=0.f,a3=0.f;
      #pragma unroll
      for (int j=0;j<16;j++){
        float4 xv = xr4[j];
        a0 = fmaf(W[j*4+0], xv.x, a0);
        a1 = fmaf(W[j*4+1], xv.y, a1);
        a2 = fmaf(W[j*4+2], xv.z, a2);
        a3 = fmaf(W[j*4+3], xv.w, a3);
      }
      float r = (a0+a1)+(a2+a3);
      if (wave==0){
        y_out[((size_t)t*B_NUM + b)*HID_D + hh*D_DIM + lane] = r;  // pre-update y
      } else {
        float e = __expf(r);
        float s = wave_sum(e);
        float val = e * __builtin_amdgcn_rcpf(s);
        (wave==1 ? q_s[buf] : k_s[buf])[lane] = val;
      }
    } else {
      const int tn = (t+1) & (S_SEQ-1);
      xl_nxt = xbase[tn*D_DIM + lane];            // coalesced prefetch
      x_lds[buf^1][lane] = xl_nxt;                // stage for step t+1
      float s0 = wave_sum(wb0*xl_cur);
      float s1 = wave_sum(wb1*xl_cur);
      float s2 = wave_sum(wb2*xl_cur);
      float s3 = wave_sum(wb3*xl_cur);
      float bb0 = __builtin_amdgcn_rcpf(1.f+__expf(-s0));
      float bb1 = __builtin_amdgcn_rcpf(1.f+__expf(-s1));
      float bb2 = __builtin_amdgcn_rcpf(1.f+__expf(-s2));
      b3_reg    = __builtin_amdgcn_rcpf(1.f+__expf(-s3));
      if (lane==0){
        beta_s[buf][0]=bb0; beta_s[buf][1]=bb1; beta_s[buf][2]=bb2;
        beta_s[buf][3]=b3_reg;
      }
    }
    __syncthreads();
    // ---- phase C ----
    if (wave < 3){
      float bw = beta_s[buf][wave];
      float a0=0.f,a1=0.f,a2=0.f,a3=0.f;
      #pragma unroll
      for (int j=0;j<16;j++){
        float4 qv = reinterpret_cast<const float4*>(q_s[buf])[j];
        float4 kv = reinterpret_cast<const float4*>(k_s[buf])[j];
        a0 = fmaf(W[j*4+0], qv.x-kv.x, a0);
        a1 = fmaf(W[j*4+1], qv.y-kv.y, a1);
        a2 = fmaf(W[j*4+2], qv.z-kv.z, a2);
        a3 = fmaf(W[j*4+3], qv.w-kv.w, a3);
      }
      float rd = (a0+a1)+(a2+a3);
      float cc = bw * rd;
      #pragma unroll
      for (int j=0;j<16;j++){
        float4 kv = reinterpret_cast<const float4*>(k_s[buf])[j];
        W[j*4+0] = fmaf(cc, kv.x, W[j*4+0]);
        W[j*4+1] = fmaf(cc, kv.y, W[j*4+1]);
        W[j*4+2] = fmaf(cc, kv.z, W[j*4+2]);
        W[j*4+3] = fmaf(cc, kv.w, W[j*4+3]);
      }
    } else {
      float qn = q_s[buf][lane], kn = k_s[buf][lane];
      float dv = qn - kn;
      float d0 = wave_sum(wb0*dv);
      float d1 = wave_sum(wb1*dv);
      float d2 = wave_sum(wb2*dv);
      float d3 = wave_sum(wb3*dv);
      float bk = b3_reg * kn;
      wb0 = fmaf(bk, d0, wb0);
      wb1 = fmaf(bk, d1, wb1);
      wb2 = fmaf(bk, d2, wb2);
      wb3 = fmaf(bk, d3, wb3);
      xl_cur = xl_nxt;
    }
  }

  // ---- final states: (W_final - p) ----
  if (wave < 3){
    const float* pp = (wave==0)? p_y : (wave==1)? p_q : p_k;
    float* o = ((wave==0)? o_sy : (wave==1)? o_sq : o_sk) + ((size_t)bh*64 + lane)*64;
    const float4* p4 = reinterpret_cast<const float4*>(pp + ((size_t)hh*64 + lane)*64);
    #pragma unroll
    for (int c=0;c<16;c++){
      float4 p = p4[c];
      float4 w;
      w.x = W[c*4+0]-p.x; w.y = W[c*4+1]-p.y; w.z = W[c*4+2]-p.z; w.w = W[c*4+3]-p.w;
      reinterpret_cast<float4*>(o)[c] = w;
    }
  } else {
    float4 pv = *reinterpret_cast<const float4*>(p_b + ((size_t)hh*64+lane)*4);
    float4 w;
    w.x = wb0-pv.x; w.y = wb1-pv.y; w.z = wb2-pv.z; w.w = wb3-pv.w;
    *reinterpret_cast<float4*>(o_sb + ((size_t)bh*64+lane)*4) = w;
  }
}

// ---------------------------------------------------------------------------
// Vector f32 GEMM: C[m][n] = sum_k A[m][k]*B[n][k] (+bias)(+Cin)(relu)
// A: [M][K] f32 row-major, Bw: [N][K] f32 row-major.
// ---------------------------------------------------------------------------
template<int BM,int BN,int TM,int TN,bool BIAS,bool RELU,bool ADDC>
__global__ __launch_bounds__(256) void gemm_k(
    const float* __restrict__ A, const float* __restrict__ Bw,
    const float* __restrict__ Cin, const float* __restrict__ bias,
    float* __restrict__ Of,
    int M, int N, int K)
{
  constexpr int BK = 16;
  constexpr int TX = BN/TN;
  constexpr int TY = BM/TM;
  static_assert(TX*TY==256, "bad tiling");
  __shared__ __align__(16) float As[BK][BM];
  __shared__ __align__(16) float Bs[BK][BN];
  const int tid = threadIdx.x;
  const int tx = tid % TX;
  const int ty = tid / TX;
  const int m0 = blockIdx.y*BM, n0 = blockIdx.x*BN;
  float acc[TM][TN] = {};

  for (int k0=0; k0<K; k0+=BK){
    { // stage A (BM rows x BK cols, transposed into As[k][m])
      constexpr int E = BM*BK/256;       // elems per thread (8 or 4)
      constexpr int TPR = BK/E;          // threads per row
      int r  = tid / TPR;
      int kk = (tid % TPR) * E;
      const float* src = A + (size_t)(m0+r)*K + k0 + kk;
      #pragma unroll
      for (int c=0;c<E;c+=4){
        float4 v = *reinterpret_cast<const float4*>(src + c);
        As[kk+c+0][r]=v.x; As[kk+c+1][r]=v.y; As[kk+c+2][r]=v.z; As[kk+c+3][r]=v.w;
      }
    }
    { // stage B
      constexpr int E = BN*BK/256;
      constexpr int TPR = BK/E;
      int r  = tid / TPR;
      int kk = (tid % TPR) * E;
      const float* src = Bw + (size_t)(n0+r)*K + k0 + kk;
      #pragma unroll
      for (int c=0;c<E;c+=4){
        float4 v = *reinterpret_cast<const float4*>(src + c);
        Bs[kk+c+0][r]=v.x; Bs[kk+c+1][r]=v.y; Bs[kk+c+2][r]=v.z; Bs[kk+c+3][r]=v.w;
      }
    }
    __syncthreads();
    #pragma unroll
    for (int kk=0;kk<BK;kk++){
      float a[TM], bf[TN];
      #pragma unroll
      for (int i=0;i<TM;i++) a[i] = As[kk][ty*TM+i];
      #pragma unroll
      for (int j=0;j<TN;j++) bf[j] = Bs[kk][tx*TN+j];
      #pragma unroll
      for (int i=0;i<TM;i++)
        #pragma unroll
        for (int j=0;j<TN;j++)
          acc[i][j] = fmaf(a[i], bf[j], acc[i][j]);
    }
    __syncthreads();
  }

  #pragma unroll
  for (int i=0;i<TM;i++){
    int row = m0 + ty*TM + i;
    #pragma unroll
    for (int j0=0;j0<TN;j0+=4){
      int col = n0 + tx*TN + j0;
      float4 v = make_float4(acc[i][j0],acc[i][j0+1],acc[i][j0+2],acc[i][j0+3]);
      if (BIAS){
        float4 bv = *reinterpret_cast<const float4*>(bias+col);
        v.x += bv.x; v.y += bv.y; v.z += bv.z; v.w += bv.w;
      }
      if (ADDC){
        float4 c = *reinterpret_cast<const float4*>(Cin + (size_t)row*N + col);
        v.x+=c.x; v.y+=c.y; v.z+=c.z; v.w+=c.w;
      }
      if (RELU){
        v.x=fmaxf(v.x,0.f); v.y=fmaxf(v.y,0.f); v.z=fmaxf(v.z,0.f); v.w=fmaxf(v.w,0.f);
      }
      *reinterpret_cast<float4*>(Of + (size_t)row*N + col) = v;
    }
  }
}

// ---------------------------------------------------------------------------
// LayerNorm over HID=512, wave per row, 8 elems/lane. f32 -> f32.
// ---------------------------------------------------------------------------
__global__ __launch_bounds__(256) void ln_k(
    const float* __restrict__ h, const float* __restrict__ g,
    const float* __restrict__ bb, float* __restrict__ out)
{
  int row  = blockIdx.x*4 + (threadIdx.x>>6);
  int lane = threadIdx.x & 63;
  const float4* hr = reinterpret_cast<const float4*>(h + (size_t)row*HID_D) + lane*2;
  float4 u = hr[0], v = hr[1];
  float vals[8] = {u.x,u.y,u.z,u.w,v.x,v.y,v.z,v.w};
  float s = 0.f;
  #pragma unroll
  for (int e=0;e<8;e++) s += vals[e];
  s = wave_sum(s);
  float mu = s * (1.f/HID_D);
  float vs = 0.f;
  #pragma unroll
  for (int e=0;e<8;e++){ float d = vals[e]-mu; vs += d*d; }
  vs = wave_sum(vs);
  float rs = rsqrtf(vs*(1.f/HID_D) + 1e-5f);
  const float4* gr = reinterpret_cast<const float4*>(g) + lane*2;
  const float4* br = reinterpret_cast<const float4*>(bb) + lane*2;
  float4 g0 = gr[0], g1 = gr[1], b0 = br[0], b1 = br[1];
  float4 o0, o1;
  o0.x = (vals[0]-mu)*rs*g0.x + b0.x;
  o0.y = (vals[1]-mu)*rs*g0.y + b0.y;
  o0.z = (vals[2]-mu)*rs*g0.z + b0.z;
  o0.w = (vals[3]-mu)*rs*g0.w + b0.w;
  o1.x = (vals[4]-mu)*rs*g1.x + b1.x;
  o1.y = (vals[5]-mu)*rs*g1.y + b1.y;
  o1.z = (vals[6]-mu)*rs*g1.z + b1.z;
  o1.w = (vals[7]-mu)*rs*g1.w + b1.w;
  float4* orow = reinterpret_cast<float4*>(out + (size_t)row*HID_D) + lane*2;
  orow[0] = o0; orow[1] = o1;
}

// ---------------------------------------------------------------------------
extern "C" void kernel_launch(void* const* d_in, const int* in_sizes, int n_in,
                              void* d_out, int out_size, void* d_ws, size_t ws_size,
                              hipStream_t stream)
{
  const float* x    = (const float*)d_in[0];
  const float* sty  = (const float*)d_in[1];
  const float* stq  = (const float*)d_in[2];
  const float* stk  = (const float*)d_in[3];
  const float* stb  = (const float*)d_in[4];
  const float* inW  = (const float*)d_in[5];
  const float* inb  = (const float*)d_in[6];
  const float* py   = (const float*)d_in[7];
  const float* pq   = (const float*)d_in[8];
  const float* pk   = (const float*)d_in[9];
  const float* pb   = (const float*)d_in[10];
  const float* Wo   = (const float*)d_in[11];
  const float* fw1  = (const float*)d_in[12];
  const float* fb1  = (const float*)d_in[13];
  const float* fw2  = (const float*)d_in[14];
  const float* fb2  = (const float*)d_in[15];
  const float* lng  = (const float*)d_in[16];
  const float* lnb  = (const float*)d_in[17];

  char* ws = (char*)d_ws;
  float* h   = (float*)ws;                  // 4 MB (2048 x 512)
  float* xsb = (float*)(ws + (4<<20));      // 4 MB (B,H,S,D)
  float* yb  = (float*)(ws + (8<<20));      // 4 MB (S,B,HID)
  float* t0  = (float*)(ws + (12<<20));     // 4 MB (ln out)
  float* t1  = (float*)(ws + (16<<20));     // 16 MB (2048 x 2048)

  float* out0 = (float*)d_out;
  const size_t OUT_SZ = (size_t)S_SEQ*B_NUM*HID_D;          // 1048576
  const size_t SYL    = (size_t)B_NUM*H_NUM*D_DIM*D_DIM;    // 262144 per layer
  const size_t SBL    = (size_t)B_NUM*H_NUM*D_DIM*4;        // 16384  per layer
  float* o_sy = out0 + OUT_SZ;
  float* o_sq = o_sy + L_NUM*SYL;
  float* o_sk = o_sq + L_NUM*SYL;
  float* o_sb = o_sk + L_NUM*SYL;

  const int M = S_SEQ*B_NUM;   // 2048
  dim3 gN512(HID_D/64, M/128); // (8,16)

  // in-projection: h = x @ in_W.T + in_b
  gemm_k<128,64,8,4,true,false,false><<<gN512,256,0,stream>>>(
      x, inW, nullptr, inb, h, M, HID_D, 512);

  for (int l=0;l<L_NUM;l++){
    softmax_xs_k<<<(S_SEQ*B_NUM*H_NUM)/4, 256, 0, stream>>>(h, xsb);

    scan4_k<<<B_NUM*H_NUM, 256, 0, stream>>>(xsb,
        sty + (size_t)l*SYL, stq + (size_t)l*SYL, stk + (size_t)l*SYL, stb + (size_t)l*SBL,
        py + (size_t)l*H_NUM*D_DIM*D_DIM, pq + (size_t)l*H_NUM*D_DIM*D_DIM,
        pk + (size_t)l*H_NUM*D_DIM*D_DIM, pb + (size_t)l*H_NUM*D_DIM*4,
        yb,
        o_sy + l*SYL, o_sq + l*SYL, o_sk + l*SYL, o_sb + l*SBL);

    // h += y @ Wo.T
    gemm_k<128,64,8,4,false,false,true><<<gN512,256,0,stream>>>(
        yb, Wo + (size_t)l*HID_D*HID_D, h, nullptr, h, M, HID_D, HID_D);

    ln_k<<<M/4,256,0,stream>>>(h, lng + l*HID_D, lnb + l*HID_D, t0);

    // t1 = relu(ln @ ff_W1.T + b1)
    gemm_k<128,128,8,8,true,true,false><<<dim3(FF_D/128, M/128),256,0,stream>>>(
        t0, fw1 + (size_t)l*FF_D*HID_D, nullptr, fb1 + l*FF_D, t1, M, FF_D, HID_D);

    // h(+out) = h + t1 @ ff_W2.T + b2   (last layer writes d_out directly)
    float* dst = (l==L_NUM-1) ? out0 : h;
    gemm_k<128,64,8,4,true,false,true><<<gN512,256,0,stream>>>(
        t1, fw2 + (size_t)l*HID_D*FF_D, h, fb2 + l*HID_D, dst, M, HID_D, FF_D);
  }
}

// Round 6
// 1198.014 us; speedup vs baseline: 2.1227x; 1.0513x over previous
//
#include <hip/hip_runtime.h>

#define L_NUM 2
#define H_NUM 8
#define D_DIM 64
#define HID_D 512
#define FF_D  2048
#define S_SEQ 256
#define B_NUM 8

// ---------------------------------------------------------------------------
// DPP wave64 sum -> uniform result on all lanes (verified R5 on HW).
// ---------------------------------------------------------------------------
__device__ __forceinline__ float wave_sum(float v){
  float t;
  t = __int_as_float(__builtin_amdgcn_update_dpp(0, __float_as_int(v), 0x111, 0xf, 0xf, false)); v += t;
  t = __int_as_float(__builtin_amdgcn_update_dpp(0, __float_as_int(v), 0x112, 0xf, 0xf, false)); v += t;
  t = __int_as_float(__builtin_amdgcn_update_dpp(0, __float_as_int(v), 0x114, 0xf, 0xf, false)); v += t;
  t = __int_as_float(__builtin_amdgcn_update_dpp(0, __float_as_int(v), 0x118, 0xf, 0xf, false)); v += t;
  t = __int_as_float(__builtin_amdgcn_update_dpp(0, __float_as_int(v), 0x142, 0xa, 0xf, false)); v += t;
  t = __int_as_float(__builtin_amdgcn_update_dpp(0, __float_as_int(v), 0x143, 0xc, 0xf, false)); v += t;
  return __int_as_float(__builtin_amdgcn_readlane(__float_as_int(v), 63));
}

// LDS-only barrier: does NOT drain vmcnt (global ops stay in flight).
__device__ __forceinline__ void lds_barrier(){
  __builtin_amdgcn_sched_barrier(0);
  asm volatile("s_waitcnt lgkmcnt(0)" ::: "memory");
  __builtin_amdgcn_s_barrier();
  __builtin_amdgcn_sched_barrier(0);
}

// ---------------------------------------------------------------------------
// Per-head softmax: h (S,B,HID) f32 -> xs (B,H,S,D) f32. One wave per 64-row.
// ---------------------------------------------------------------------------
__global__ __launch_bounds__(256) void softmax_xs_k(
    const float* __restrict__ h, float* __restrict__ xs)
{
  int rid  = blockIdx.x*4 + (threadIdx.x>>6);   // (s*B+b)*H + hd
  int lane = threadIdx.x & 63;
  int hd = rid & (H_NUM-1);
  int sb = rid >> 3;                            // s*B + b
  int b  = sb & (B_NUM-1);
  int s  = sb >> 3;
  float v = h[(size_t)sb*HID_D + hd*D_DIM + lane];
  float m = v;
  #pragma unroll
  for (int off=32; off; off>>=1) m = fmaxf(m, __shfl_xor(m, off));
  float e = __expf(v-m);
  float sum = wave_sum(e);
  xs[(((size_t)(b*H_NUM+hd))*S_SEQ + s)*D_DIM + lane] = e/sum;
}

// ---------------------------------------------------------------------------
// SRWM scan, 4 waves per (b,h): wave0 Wy, wave1 Wq, wave2 Wk, wave3 wb.
// Steady-state has ZERO global ops on the barrier path: x octet-batched in
// regs (8 loads / 8 steps, hidden), y stores fire-and-forget (raw barrier).
// ---------------------------------------------------------------------------
__global__ __launch_bounds__(256,1) void scan4_k(
    const float* __restrict__ xs,                 // (B,H,S,D) f32
    const float* __restrict__ st_y, const float* __restrict__ st_q,
    const float* __restrict__ st_k, const float* __restrict__ st_b,
    const float* __restrict__ p_y,  const float* __restrict__ p_q,
    const float* __restrict__ p_k,  const float* __restrict__ p_b,
    float* __restrict__ y_out,                    // (S,B,HID) f32
    float* __restrict__ o_sy, float* __restrict__ o_sq,
    float* __restrict__ o_sk, float* __restrict__ o_sb)
{
  const int bh = blockIdx.x;
  const int b  = bh >> 3, hh = bh & 7;
  const int wave = threadIdx.x >> 6, lane = threadIdx.x & 63;

  __shared__ __align__(16) float q_s[2][64];
  __shared__ __align__(16) float k_s[2][64];
  __shared__ __align__(16) float x_lds[2][64];
  __shared__ float beta_s[2][4];

  float W[64];                                   // waves 0-2: row `lane`
  float wb0=0.f, wb1=0.f, wb2=0.f, wb3=0.f;      // wave 3
  float xr[8], xn[8];                            // wave 3: x octet dbl-buf
  float b3_reg=0.f;

  if (wave < 3) {
    const float* st = (wave==0)? st_y : (wave==1)? st_q : st_k;
    const float* pp = (wave==0)? p_y  : (wave==1)? p_q  : p_k;
    const float4* s4 = reinterpret_cast<const float4*>(st + ((size_t)bh*64 + lane)*64);
    const float4* p4 = reinterpret_cast<const float4*>(pp + ((size_t)hh*64 + lane)*64);
    #pragma unroll
    for (int c=0;c<16;c++){
      float4 a = s4[c], p = p4[c];
      W[c*4+0]=a.x+p.x; W[c*4+1]=a.y+p.y; W[c*4+2]=a.z+p.z; W[c*4+3]=a.w+p.w;
    }
  } else {
    float4 sv = *reinterpret_cast<const float4*>(st_b + ((size_t)bh*64+lane)*4);
    float4 pv = *reinterpret_cast<const float4*>(p_b  + ((size_t)hh*64+lane)*4);
    wb0 = sv.x+pv.x; wb1 = sv.y+pv.y; wb2 = sv.z+pv.z; wb3 = sv.w+pv.w;
  }

  const float* xbase = xs + (size_t)bh * (S_SEQ*D_DIM);
  if (wave == 3){
    #pragma unroll
    for (int i=0;i<8;i++) xr[i] = xbase[i*D_DIM + lane];
    x_lds[0][lane] = xr[0];
  }
  __syncthreads();

  for (int t0=0; t0<S_SEQ; t0+=8){
    #pragma unroll
    for (int i=0;i<8;i++){
      const int t = t0 + i;
      const int buf = i & 1;                     // == t&1 (t0 multiple of 8)
      // ---- phase A ----
      if (wave < 3){
        const float4* xr4 = reinterpret_cast<const float4*>(x_lds[buf]);
        float a0=0.f,a1=0.f,a2=0.f,a3=0.f;
        #pragma unroll
        for (int j=0;j<16;j++){
          float4 xv = xr4[j];
          a0 = fmaf(W[j*4+0], xv.x, a0);
          a1 = fmaf(W[j*4+1], xv.y, a1);
          a2 = fmaf(W[j*4+2], xv.z, a2);
          a3 = fmaf(W[j*4+3], xv.w, a3);
        }
        float r = (a0+a1)+(a2+a3);
        if (wave==0){
          y_out[((size_t)t*B_NUM + b)*HID_D + hh*D_DIM + lane] = r;  // no drain
        } else {
          float e = __expf(r);
          float s = wave_sum(e);
          float val = e * __builtin_amdgcn_rcpf(s);
          (wave==1 ? q_s[buf] : k_s[buf])[lane] = val;
        }
      } else {
        if (i == 0){
          // issue next-octet loads; consumed 7+ steps later (fully hidden)
          #pragma unroll
          for (int ii=0;ii<8;ii++){
            const int tt = (t0+8+ii) & (S_SEQ-1);
            xn[ii] = xbase[tt*D_DIM + lane];
          }
        }
        // stage x_{t+1} for next step from REGISTERS (no global dep)
        x_lds[buf^1][lane] = (i<7) ? xr[i+1] : xn[0];
        float xl = xr[i];
        float s0 = wave_sum(wb0*xl);
        float s1 = wave_sum(wb1*xl);
        float s2 = wave_sum(wb2*xl);
        float s3 = wave_sum(wb3*xl);
        float bb0 = __builtin_amdgcn_rcpf(1.f+__expf(-s0));
        float bb1 = __builtin_amdgcn_rcpf(1.f+__expf(-s1));
        float bb2 = __builtin_amdgcn_rcpf(1.f+__expf(-s2));
        b3_reg    = __builtin_amdgcn_rcpf(1.f+__expf(-s3));
        if (lane==0){
          beta_s[buf][0]=bb0; beta_s[buf][1]=bb1; beta_s[buf][2]=bb2;
          beta_s[buf][3]=b3_reg;
        }
      }
      lds_barrier();
      // ---- phase C ----
      if (wave < 3){
        float bw = beta_s[buf][wave];
        float kr[64];                            // stash k for update loop
        float a0=0.f,a1=0.f,a2=0.f,a3=0.f;
        #pragma unroll
        for (int j=0;j<16;j++){
          float4 qv = reinterpret_cast<const float4*>(q_s[buf])[j];
          float4 kv = reinterpret_cast<const float4*>(k_s[buf])[j];
          kr[j*4+0]=kv.x; kr[j*4+1]=kv.y; kr[j*4+2]=kv.z; kr[j*4+3]=kv.w;
          a0 = fmaf(W[j*4+0], qv.x-kv.x, a0);
          a1 = fmaf(W[j*4+1], qv.y-kv.y, a1);
          a2 = fmaf(W[j*4+2], qv.z-kv.z, a2);
          a3 = fmaf(W[j*4+3], qv.w-kv.w, a3);
        }
        float rd = (a0+a1)+(a2+a3);
        float cc = bw * rd;
        #pragma unroll
        for (int j=0;j<64;j++)
          W[j] = fmaf(cc, kr[j], W[j]);
      } else {
        float qn = q_s[buf][lane], kn = k_s[buf][lane];
        float dv = qn - kn;
        float d0 = wave_sum(wb0*dv);
        float d1 = wave_sum(wb1*dv);
        float d2 = wave_sum(wb2*dv);
        float d3 = wave_sum(wb3*dv);
        float bk = b3_reg * kn;
        wb0 = fmaf(bk, d0, wb0);
        wb1 = fmaf(bk, d1, wb1);
        wb2 = fmaf(bk, d2, wb2);
        wb3 = fmaf(bk, d3, wb3);
      }
    }
    if (wave == 3){
      #pragma unroll
      for (int i=0;i<8;i++) xr[i] = xn[i];
    }
  }

  // ---- final states: (W_final - p) ----
  if (wave < 3){
    const float* pp = (wave==0)? p_y : (wave==1)? p_q : p_k;
    float* o = ((wave==0)? o_sy : (wave==1)? o_sq : o_sk) + ((size_t)bh*64 + lane)*64;
    const float4* p4 = reinterpret_cast<const float4*>(pp + ((size_t)hh*64 + lane)*64);
    #pragma unroll
    for (int c=0;c<16;c++){
      float4 p = p4[c];
      float4 w;
      w.x = W[c*4+0]-p.x; w.y = W[c*4+1]-p.y; w.z = W[c*4+2]-p.z; w.w = W[c*4+3]-p.w;
      reinterpret_cast<float4*>(o)[c] = w;
    }
  } else {
    float4 pv = *reinterpret_cast<const float4*>(p_b + ((size_t)hh*64+lane)*4);
    float4 w;
    w.x = wb0-pv.x; w.y = wb1-pv.y; w.z = wb2-pv.z; w.w = wb3-pv.w;
    *reinterpret_cast<float4*>(o_sb + ((size_t)bh*64+lane)*4) = w;
  }
}

// ---------------------------------------------------------------------------
// Vector f32 GEMM: C[m][n] = sum_k A[m][k]*B[n][k] (+bias)(+Cin)(relu)
// A: [M][K] f32 row-major, Bw: [N][K] f32 row-major.
// ---------------------------------------------------------------------------
template<int BM,int BN,int TM,int TN,bool BIAS,bool RELU,bool ADDC>
__global__ __launch_bounds__(256) void gemm_k(
    const float* __restrict__ A, const float* __restrict__ Bw,
    const float* __restrict__ Cin, const float* __restrict__ bias,
    float* __restrict__ Of,
    int M, int N, int K)
{
  constexpr int BK = 16;
  constexpr int TX = BN/TN;
  constexpr int TY = BM/TM;
  static_assert(TX*TY==256, "bad tiling");
  __shared__ __align__(16) float As[BK][BM];
  __shared__ __align__(16) float Bs[BK][BN];
  const int tid = threadIdx.x;
  const int tx = tid % TX;
  const int ty = tid / TX;
  const int m0 = blockIdx.y*BM, n0 = blockIdx.x*BN;
  float acc[TM][TN] = {};

  for (int k0=0; k0<K; k0+=BK){
    { // stage A (BM rows x BK cols, transposed into As[k][m])
      constexpr int E = BM*BK/256;       // elems per thread (8 or 4)
      constexpr int TPR = BK/E;          // threads per row
      int r  = tid / TPR;
      int kk = (tid % TPR) * E;
      const float* src = A + (size_t)(m0+r)*K + k0 + kk;
      #pragma unroll
      for (int c=0;c<E;c+=4){
        float4 v = *reinterpret_cast<const float4*>(src + c);
        As[kk+c+0][r]=v.x; As[kk+c+1][r]=v.y; As[kk+c+2][r]=v.z; As[kk+c+3][r]=v.w;
      }
    }
    { // stage B
      constexpr int E = BN*BK/256;
      constexpr int TPR = BK/E;
      int r  = tid / TPR;
      int kk = (tid % TPR) * E;
      const float* src = Bw + (size_t)(n0+r)*K + k0 + kk;
      #pragma unroll
      for (int c=0;c<E;c+=4){
        float4 v = *reinterpret_cast<const float4*>(src + c);
        Bs[kk+c+0][r]=v.x; Bs[kk+c+1][r]=v.y; Bs[kk+c+2][r]=v.z; Bs[kk+c+3][r]=v.w;
      }
    }
    __syncthreads();
    #pragma unroll
    for (int kk=0;kk<BK;kk++){
      float a[TM], bf[TN];
      #pragma unroll
      for (int i=0;i<TM;i++) a[i] = As[kk][ty*TM+i];
      #pragma unroll
      for (int j=0;j<TN;j++) bf[j] = Bs[kk][tx*TN+j];
      #pragma unroll
      for (int i=0;i<TM;i++)
        #pragma unroll
        for (int j=0;j<TN;j++)
          acc[i][j] = fmaf(a[i], bf[j], acc[i][j]);
    }
    __syncthreads();
  }

  #pragma unroll
  for (int i=0;i<TM;i++){
    int row = m0 + ty*TM + i;
    #pragma unroll
    for (int j0=0;j0<TN;j0+=4){
      int col = n0 + tx*TN + j0;
      float4 v = make_float4(acc[i][j0],acc[i][j0+1],acc[i][j0+2],acc[i][j0+3]);
      if (BIAS){
        float4 bv = *reinterpret_cast<const float4*>(bias+col);
        v.x += bv.x; v.y += bv.y; v.z += bv.z; v.w += bv.w;
      }
      if (ADDC){
        float4 c = *reinterpret_cast<const float4*>(Cin + (size_t)row*N + col);
        v.x+=c.x; v.y+=c.y; v.z+=c.z; v.w+=c.w;
      }
      if (RELU){
        v.x=fmaxf(v.x,0.f); v.y=fmaxf(v.y,0.f); v.z=fmaxf(v.z,0.f); v.w=fmaxf(v.w,0.f);
      }
      *reinterpret_cast<float4*>(Of + (size_t)row*N + col) = v;
    }
  }
}

// ---------------------------------------------------------------------------
// LayerNorm over HID=512, wave per row, 8 elems/lane. f32 -> f32.
// ---------------------------------------------------------------------------
__global__ __launch_bounds__(256) void ln_k(
    const float* __restrict__ h, const float* __restrict__ g,
    const float* __restrict__ bb, float* __restrict__ out)
{
  int row  = blockIdx.x*4 + (threadIdx.x>>6);
  int lane = threadIdx.x & 63;
  const float4* hr = reinterpret_cast<const float4*>(h + (size_t)row*HID_D) + lane*2;
  float4 u = hr[0], v = hr[1];
  float vals[8] = {u.x,u.y,u.z,u.w,v.x,v.y,v.z,v.w};
  float s = 0.f;
  #pragma unroll
  for (int e=0;e<8;e++) s += vals[e];
  s = wave_sum(s);
  float mu = s * (1.f/HID_D);
  float vs = 0.f;
  #pragma unroll
  for (int e=0;e<8;e++){ float d = vals[e]-mu; vs += d*d; }
  vs = wave_sum(vs);
  float rs = rsqrtf(vs*(1.f/HID_D) + 1e-5f);
  const float4* gr = reinterpret_cast<const float4*>(g) + lane*2;
  const float4* br = reinterpret_cast<const float4*>(bb) + lane*2;
  float4 g0 = gr[0], g1 = gr[1], b0 = br[0], b1 = br[1];
  float4 o0, o1;
  o0.x = (vals[0]-mu)*rs*g0.x + b0.x;
  o0.y = (vals[1]-mu)*rs*g0.y + b0.y;
  o0.z = (vals[2]-mu)*rs*g0.z + b0.z;
  o0.w = (vals[3]-mu)*rs*g0.w + b0.w;
  o1.x = (vals[4]-mu)*rs*g1.x + b1.x;
  o1.y = (vals[5]-mu)*rs*g1.y + b1.y;
  o1.z = (vals[6]-mu)*rs*g1.z + b1.z;
  o1.w = (vals[7]-mu)*rs*g1.w + b1.w;
  float4* orow = reinterpret_cast<float4*>(out + (size_t)row*HID_D) + lane*2;
  orow[0] = o0; orow[1] = o1;
}

// ---------------------------------------------------------------------------
extern "C" void kernel_launch(void* const* d_in, const int* in_sizes, int n_in,
                              void* d_out, int out_size, void* d_ws, size_t ws_size,
                              hipStream_t stream)
{
  const float* x    = (const float*)d_in[0];
  const float* sty  = (const float*)d_in[1];
  const float* stq  = (const float*)d_in[2];
  const float* stk  = (const float*)d_in[3];
  const float* stb  = (const float*)d_in[4];
  const float* inW  = (const float*)d_in[5];
  const float* inb  = (const float*)d_in[6];
  const float* py   = (const float*)d_in[7];
  const float* pq   = (const float*)d_in[8];
  const float* pk   = (const float*)d_in[9];
  const float* pb   = (const float*)d_in[10];
  const float* Wo   = (const float*)d_in[11];
  const float* fw1  = (const float*)d_in[12];
  const float* fb1  = (const float*)d_in[13];
  const float* fw2  = (const float*)d_in[14];
  const float* fb2  = (const float*)d_in[15];
  const float* lng  = (const float*)d_in[16];
  const float* lnb  = (const float*)d_in[17];

  char* ws = (char*)d_ws;
  float* h   = (float*)ws;                  // 4 MB (2048 x 512)
  float* xsb = (float*)(ws + (4<<20));      // 4 MB (B,H,S,D)
  float* yb  = (float*)(ws + (8<<20));      // 4 MB (S,B,HID)
  float* t0  = (float*)(ws + (12<<20));     // 4 MB (ln out)
  float* t1  = (float*)(ws + (16<<20));     // 16 MB (2048 x 2048)

  float* out0 = (float*)d_out;
  const size_t OUT_SZ = (size_t)S_SEQ*B_NUM*HID_D;          // 1048576
  const size_t SYL    = (size_t)B_NUM*H_NUM*D_DIM*D_DIM;    // 262144 per layer
  const size_t SBL    = (size_t)B_NUM*H_NUM*D_DIM*4;        // 16384  per layer
  float* o_sy = out0 + OUT_SZ;
  float* o_sq = o_sy + L_NUM*SYL;
  float* o_sk = o_sq + L_NUM*SYL;
  float* o_sb = o_sk + L_NUM*SYL;

  const int M = S_SEQ*B_NUM;   // 2048
  dim3 gN512(HID_D/64, M/128); // (8,16)

  // in-projection: h = x @ in_W.T + in_b
  gemm_k<128,64,8,4,true,false,false><<<gN512,256,0,stream>>>(
      x, inW, nullptr, inb, h, M, HID_D, 512);

  for (int l=0;l<L_NUM;l++){
    softmax_xs_k<<<(S_SEQ*B_NUM*H_NUM)/4, 256, 0, stream>>>(h, xsb);

    scan4_k<<<B_NUM*H_NUM, 256, 0, stream>>>(xsb,
        sty + (size_t)l*SYL, stq + (size_t)l*SYL, stk + (size_t)l*SYL, stb + (size_t)l*SBL,
        py + (size_t)l*H_NUM*D_DIM*D_DIM, pq + (size_t)l*H_NUM*D_DIM*D_DIM,
        pk + (size_t)l*H_NUM*D_DIM*D_DIM, pb + (size_t)l*H_NUM*D_DIM*4,
        yb,
        o_sy + l*SYL, o_sq + l*SYL, o_sk + l*SYL, o_sb + l*SBL);

    // h += y @ Wo.T
    gemm_k<128,64,8,4,false,false,true><<<gN512,256,0,stream>>>(
        yb, Wo + (size_t)l*HID_D*HID_D, h, nullptr, h, M, HID_D, HID_D);

    ln_k<<<M/4,256,0,stream>>>(h, lng + l*HID_D, lnb + l*HID_D, t0);

    // t1 = relu(ln @ ff_W1.T + b1)
    gemm_k<128,128,8,8,true,true,false><<<dim3(FF_D/128, M/128),256,0,stream>>>(
        t0, fw1 + (size_t)l*FF_D*HID_D, nullptr, fb1 + l*FF_D, t1, M, FF_D, HID_D);

    // h(+out) = h + t1 @ ff_W2.T + b2   (last layer writes d_out directly)
    float* dst = (l==L_NUM-1) ? out0 : h;
    gemm_k<128,64,8,4,true,false,true><<<gN512,256,0,stream>>>(
        t1, fw2 + (size_t)l*HID_D*FF_D, h, fb2 + l*HID_D, dst, M, HID_D, FF_D);
  }
}

// Round 7
// 908.336 us; speedup vs baseline: 2.7997x; 1.3189x over previous
//
#include <hip/hip_runtime.h>

#define L_NUM 2
#define H_NUM 8
#define D_DIM 64
#define HID_D 512
#define FF_D  2048
#define S_SEQ 256
#define B_NUM 8

typedef unsigned short u16;
typedef unsigned int   u32;
typedef __attribute__((ext_vector_type(8))) short bf16x8;
typedef __attribute__((ext_vector_type(4))) float f32x4;

__device__ __forceinline__ u16 f2bu(float f){
  u32 u = __float_as_uint(f);
  u32 r = (u + 0x7fffu + ((u>>16)&1u)) >> 16;   // RNE to bf16
  return (u16)r;
}

// ---------------------------------------------------------------------------
// DPP wave64 sum -> uniform result on all lanes (verified on HW).
// ---------------------------------------------------------------------------
__device__ __forceinline__ float wave_sum(float v){
  float t;
  t = __int_as_float(__builtin_amdgcn_update_dpp(0, __float_as_int(v), 0x111, 0xf, 0xf, false)); v += t;
  t = __int_as_float(__builtin_amdgcn_update_dpp(0, __float_as_int(v), 0x112, 0xf, 0xf, false)); v += t;
  t = __int_as_float(__builtin_amdgcn_update_dpp(0, __float_as_int(v), 0x114, 0xf, 0xf, false)); v += t;
  t = __int_as_float(__builtin_amdgcn_update_dpp(0, __float_as_int(v), 0x118, 0xf, 0xf, false)); v += t;
  t = __int_as_float(__builtin_amdgcn_update_dpp(0, __float_as_int(v), 0x142, 0xa, 0xf, false)); v += t;
  t = __int_as_float(__builtin_amdgcn_update_dpp(0, __float_as_int(v), 0x143, 0xc, 0xf, false)); v += t;
  return __int_as_float(__builtin_amdgcn_readlane(__float_as_int(v), 63));
}

// LDS-only barrier: does NOT drain vmcnt (global ops stay in flight).
__device__ __forceinline__ void lds_barrier(){
  __builtin_amdgcn_sched_barrier(0);
  asm volatile("s_waitcnt lgkmcnt(0)" ::: "memory");
  __builtin_amdgcn_s_barrier();
  __builtin_amdgcn_sched_barrier(0);
}

// ---------------------------------------------------------------------------
// Per-head softmax: h (S,B,HID) f32 -> xs (B,H,S,D) f32. One wave per 64-row.
// ---------------------------------------------------------------------------
__global__ __launch_bounds__(256) void softmax_xs_k(
    const float* __restrict__ h, float* __restrict__ xs)
{
  int rid  = blockIdx.x*4 + (threadIdx.x>>6);   // (s*B+b)*H + hd
  int lane = threadIdx.x & 63;
  int hd = rid & (H_NUM-1);
  int sb = rid >> 3;                            // s*B + b
  int b  = sb & (B_NUM-1);
  int s  = sb >> 3;
  float v = h[(size_t)sb*HID_D + hd*D_DIM + lane];
  float m = v;
  #pragma unroll
  for (int off=32; off; off>>=1) m = fmaxf(m, __shfl_xor(m, off));
  float e = __expf(v-m);
  float sum = wave_sum(e);
  xs[(((size_t)(b*H_NUM+hd))*S_SEQ + s)*D_DIM + lane] = e/sum;
}

// ---------------------------------------------------------------------------
// SRWM scan, 4 waves per (b,h) — identical to R6 passing version.
// ---------------------------------------------------------------------------
__global__ __launch_bounds__(256,1) void scan4_k(
    const float* __restrict__ xs,
    const float* __restrict__ st_y, const float* __restrict__ st_q,
    const float* __restrict__ st_k, const float* __restrict__ st_b,
    const float* __restrict__ p_y,  const float* __restrict__ p_q,
    const float* __restrict__ p_k,  const float* __restrict__ p_b,
    float* __restrict__ y_out,
    float* __restrict__ o_sy, float* __restrict__ o_sq,
    float* __restrict__ o_sk, float* __restrict__ o_sb)
{
  const int bh = blockIdx.x;
  const int b  = bh >> 3, hh = bh & 7;
  const int wave = threadIdx.x >> 6, lane = threadIdx.x & 63;

  __shared__ __align__(16) float q_s[2][64];
  __shared__ __align__(16) float k_s[2][64];
  __shared__ __align__(16) float x_lds[2][64];
  __shared__ float beta_s[2][4];

  float W[64];
  float wb0=0.f, wb1=0.f, wb2=0.f, wb3=0.f;
  float xr[8], xn[8];
  float b3_reg=0.f;

  if (wave < 3) {
    const float* st = (wave==0)? st_y : (wave==1)? st_q : st_k;
    const float* pp = (wave==0)? p_y  : (wave==1)? p_q  : p_k;
    const float4* s4 = reinterpret_cast<const float4*>(st + ((size_t)bh*64 + lane)*64);
    const float4* p4 = reinterpret_cast<const float4*>(pp + ((size_t)hh*64 + lane)*64);
    #pragma unroll
    for (int c=0;c<16;c++){
      float4 a = s4[c], p = p4[c];
      W[c*4+0]=a.x+p.x; W[c*4+1]=a.y+p.y; W[c*4+2]=a.z+p.z; W[c*4+3]=a.w+p.w;
    }
  } else {
    float4 sv = *reinterpret_cast<const float4*>(st_b + ((size_t)bh*64+lane)*4);
    float4 pv = *reinterpret_cast<const float4*>(p_b  + ((size_t)hh*64+lane)*4);
    wb0 = sv.x+pv.x; wb1 = sv.y+pv.y; wb2 = sv.z+pv.z; wb3 = sv.w+pv.w;
  }

  const float* xbase = xs + (size_t)bh * (S_SEQ*D_DIM);
  if (wave == 3){
    #pragma unroll
    for (int i=0;i<8;i++) xr[i] = xbase[i*D_DIM + lane];
    x_lds[0][lane] = xr[0];
  }
  __syncthreads();

  for (int t0=0; t0<S_SEQ; t0+=8){
    #pragma unroll
    for (int i=0;i<8;i++){
      const int t = t0 + i;
      const int buf = i & 1;
      if (wave < 3){
        const float4* xr4 = reinterpret_cast<const float4*>(x_lds[buf]);
        float a0=0.f,a1=0.f,a2=0.f,a3=0.f;
        #pragma unroll
        for (int j=0;j<16;j++){
          float4 xv = xr4[j];
          a0 = fmaf(W[j*4+0], xv.x, a0);
          a1 = fmaf(W[j*4+1], xv.y, a1);
          a2 = fmaf(W[j*4+2], xv.z, a2);
          a3 = fmaf(W[j*4+3], xv.w, a3);
        }
        float r = (a0+a1)+(a2+a3);
        if (wave==0){
          y_out[((size_t)t*B_NUM + b)*HID_D + hh*D_DIM + lane] = r;
        } else {
          float e = __expf(r);
          float s = wave_sum(e);
          float val = e * __builtin_amdgcn_rcpf(s);
          (wave==1 ? q_s[buf] : k_s[buf])[lane] = val;
        }
      } else {
        if (i == 0){
          #pragma unroll
          for (int ii=0;ii<8;ii++){
            const int tt = (t0+8+ii) & (S_SEQ-1);
            xn[ii] = xbase[tt*D_DIM + lane];
          }
        }
        x_lds[buf^1][lane] = (i<7) ? xr[i+1] : xn[0];
        float xl = xr[i];
        float s0 = wave_sum(wb0*xl);
        float s1 = wave_sum(wb1*xl);
        float s2 = wave_sum(wb2*xl);
        float s3 = wave_sum(wb3*xl);
        float bb0 = __builtin_amdgcn_rcpf(1.f+__expf(-s0));
        float bb1 = __builtin_amdgcn_rcpf(1.f+__expf(-s1));
        float bb2 = __builtin_amdgcn_rcpf(1.f+__expf(-s2));
        b3_reg    = __builtin_amdgcn_rcpf(1.f+__expf(-s3));
        if (lane==0){
          beta_s[buf][0]=bb0; beta_s[buf][1]=bb1; beta_s[buf][2]=bb2;
          beta_s[buf][3]=b3_reg;
        }
      }
      lds_barrier();
      if (wave < 3){
        float bw = beta_s[buf][wave];
        float kr[64];
        float a0=0.f,a1=0.f,a2=0.f,a3=0.f;
        #pragma unroll
        for (int j=0;j<16;j++){
          float4 qv = reinterpret_cast<const float4*>(q_s[buf])[j];
          float4 kv = reinterpret_cast<const float4*>(k_s[buf])[j];
          kr[j*4+0]=kv.x; kr[j*4+1]=kv.y; kr[j*4+2]=kv.z; kr[j*4+3]=kv.w;
          a0 = fmaf(W[j*4+0], qv.x-kv.x, a0);
          a1 = fmaf(W[j*4+1], qv.y-kv.y, a1);
          a2 = fmaf(W[j*4+2], qv.z-kv.z, a2);
          a3 = fmaf(W[j*4+3], qv.w-kv.w, a3);
        }
        float rd = (a0+a1)+(a2+a3);
        float cc = bw * rd;
        #pragma unroll
        for (int j=0;j<64;j++)
          W[j] = fmaf(cc, kr[j], W[j]);
      } else {
        float qn = q_s[buf][lane], kn = k_s[buf][lane];
        float dv = qn - kn;
        float d0 = wave_sum(wb0*dv);
        float d1 = wave_sum(wb1*dv);
        float d2 = wave_sum(wb2*dv);
        float d3 = wave_sum(wb3*dv);
        float bk = b3_reg * kn;
        wb0 = fmaf(bk, d0, wb0);
        wb1 = fmaf(bk, d1, wb1);
        wb2 = fmaf(bk, d2, wb2);
        wb3 = fmaf(bk, d3, wb3);
      }
    }
    if (wave == 3){
      #pragma unroll
      for (int i=0;i<8;i++) xr[i] = xn[i];
    }
  }

  if (wave < 3){
    const float* pp = (wave==0)? p_y : (wave==1)? p_q : p_k;
    float* o = ((wave==0)? o_sy : (wave==1)? o_sq : o_sk) + ((size_t)bh*64 + lane)*64;
    const float4* p4 = reinterpret_cast<const float4*>(pp + ((size_t)hh*64 + lane)*64);
    #pragma unroll
    for (int c=0;c<16;c++){
      float4 p = p4[c];
      float4 w;
      w.x = W[c*4+0]-p.x; w.y = W[c*4+1]-p.y; w.z = W[c*4+2]-p.z; w.w = W[c*4+3]-p.w;
      reinterpret_cast<float4*>(o)[c] = w;
    }
  } else {
    float4 pv = *reinterpret_cast<const float4*>(p_b + ((size_t)hh*64+lane)*4);
    float4 w;
    w.x = wb0-pv.x; w.y = wb1-pv.y; w.z = wb2-pv.z; w.w = wb3-pv.w;
    *reinterpret_cast<float4*>(o_sb + ((size_t)bh*64+lane)*4) = w;
  }
}

// ---------------------------------------------------------------------------
// bf16 MFMA GEMM: C[m][n] = sum_k A[m][k]*B[n][k] (+bias)(+Cin)(relu), f32 I/O.
// f32->bf16 cast fused into LDS staging. Tile 128x128, BK=32, 4 waves,
// 16x16x32 MFMA, each wave owns a 64x64 sub-tile (4x4 fragments).
// ---------------------------------------------------------------------------
template<bool BIAS,bool RELU,bool ADDC>
__global__ __launch_bounds__(256) void mgemm_k(
    const float* __restrict__ A, const float* __restrict__ Bw,
    const float* __restrict__ Cin, const float* __restrict__ bias,
    float* __restrict__ Of,
    int M, int N, int K)
{
  constexpr int BK = 32;
  constexpr int LDT = 40;                       // padded row stride (80 B)
  __shared__ __align__(16) u16 As[128][LDT];
  __shared__ __align__(16) u16 Bs[128][LDT];

  const int tid  = threadIdx.x;
  const int wv   = tid >> 6;
  const int lane = tid & 63;
  const int wr   = (wv >> 1) * 64;              // wave row origin in tile
  const int wc   = (wv & 1) * 64;               // wave col origin in tile
  const int lr   = lane & 15;
  const int lg   = lane >> 4;
  const int m0 = blockIdx.y * 128, n0 = blockIdx.x * 128;

  // staging coords: 2 threads per row, 16 k-elems each
  const int sr = tid >> 1;
  const int sk = (tid & 1) * 16;

  f32x4 acc[4][4] = {};

  for (int kt = 0; kt < K; kt += BK){
    { // stage A: 128 rows x 32 k, f32 -> bf16
      const float4* src = reinterpret_cast<const float4*>(A + (size_t)(m0+sr)*K + kt + sk);
      u16 tmp[16];
      #pragma unroll
      for (int c=0;c<4;c++){
        float4 v = src[c];
        tmp[c*4+0]=f2bu(v.x); tmp[c*4+1]=f2bu(v.y);
        tmp[c*4+2]=f2bu(v.z); tmp[c*4+3]=f2bu(v.w);
      }
      #pragma unroll
      for (int c=0;c<2;c++)
        *reinterpret_cast<uint4*>(&As[sr][sk + c*8]) = *reinterpret_cast<uint4*>(&tmp[c*8]);
    }
    { // stage B
      const float4* src = reinterpret_cast<const float4*>(Bw + (size_t)(n0+sr)*K + kt + sk);
      u16 tmp[16];
      #pragma unroll
      for (int c=0;c<4;c++){
        float4 v = src[c];
        tmp[c*4+0]=f2bu(v.x); tmp[c*4+1]=f2bu(v.y);
        tmp[c*4+2]=f2bu(v.z); tmp[c*4+3]=f2bu(v.w);
      }
      #pragma unroll
      for (int c=0;c<2;c++)
        *reinterpret_cast<uint4*>(&Bs[sr][sk + c*8]) = *reinterpret_cast<uint4*>(&tmp[c*8]);
    }
    __syncthreads();

    bf16x8 af[4], bf[4];
    #pragma unroll
    for (int i=0;i<4;i++)
      af[i] = *reinterpret_cast<const bf16x8*>(&As[wr + i*16 + lr][lg*8]);
    #pragma unroll
    for (int j=0;j<4;j++)
      bf[j] = *reinterpret_cast<const bf16x8*>(&Bs[wc + j*16 + lr][lg*8]);
    #pragma unroll
    for (int i=0;i<4;i++)
      #pragma unroll
      for (int j=0;j<4;j++)
        acc[i][j] = __builtin_amdgcn_mfma_f32_16x16x32_bf16(af[i], bf[j], acc[i][j], 0,0,0);

    __syncthreads();
  }

  // epilogue: D mapping col=lane&15, row=(lane>>4)*4+dj  [m89-verified]
  #pragma unroll
  for (int j=0;j<4;j++){
    const int col = n0 + wc + j*16 + lr;
    float bv = 0.f;
    if (BIAS) bv = bias[col];
    #pragma unroll
    for (int i=0;i<4;i++){
      const int rbase = m0 + wr + i*16 + lg*4;
      #pragma unroll
      for (int dj=0;dj<4;dj++){
        const int row = rbase + dj;
        float v = acc[i][j][dj];
        if (BIAS) v += bv;
        if (ADDC) v += Cin[(size_t)row*N + col];
        if (RELU) v = fmaxf(v, 0.f);
        Of[(size_t)row*N + col] = v;
      }
    }
  }
}

// ---------------------------------------------------------------------------
// LayerNorm over HID=512, wave per row, 8 elems/lane. f32 -> f32.
// ---------------------------------------------------------------------------
__global__ __launch_bounds__(256) void ln_k(
    const float* __restrict__ h, const float* __restrict__ g,
    const float* __restrict__ bb, float* __restrict__ out)
{
  int row  = blockIdx.x*4 + (threadIdx.x>>6);
  int lane = threadIdx.x & 63;
  const float4* hr = reinterpret_cast<const float4*>(h + (size_t)row*HID_D) + lane*2;
  float4 u = hr[0], v = hr[1];
  float vals[8] = {u.x,u.y,u.z,u.w,v.x,v.y,v.z,v.w};
  float s = 0.f;
  #pragma unroll
  for (int e=0;e<8;e++) s += vals[e];
  s = wave_sum(s);
  float mu = s * (1.f/HID_D);
  float vs = 0.f;
  #pragma unroll
  for (int e=0;e<8;e++){ float d = vals[e]-mu; vs += d*d; }
  vs = wave_sum(vs);
  float rs = rsqrtf(vs*(1.f/HID_D) + 1e-5f);
  const float4* gr = reinterpret_cast<const float4*>(g) + lane*2;
  const float4* br = reinterpret_cast<const float4*>(bb) + lane*2;
  float4 g0 = gr[0], g1 = gr[1], b0 = br[0], b1 = br[1];
  float4 o0, o1;
  o0.x = (vals[0]-mu)*rs*g0.x + b0.x;
  o0.y = (vals[1]-mu)*rs*g0.y + b0.y;
  o0.z = (vals[2]-mu)*rs*g0.z + b0.z;
  o0.w = (vals[3]-mu)*rs*g0.w + b0.w;
  o1.x = (vals[4]-mu)*rs*g1.x + b1.x;
  o1.y = (vals[5]-mu)*rs*g1.y + b1.y;
  o1.z = (vals[6]-mu)*rs*g1.z + b1.z;
  o1.w = (vals[7]-mu)*rs*g1.w + b1.w;
  float4* orow = reinterpret_cast<float4*>(out + (size_t)row*HID_D) + lane*2;
  orow[0] = o0; orow[1] = o1;
}

// ---------------------------------------------------------------------------
extern "C" void kernel_launch(void* const* d_in, const int* in_sizes, int n_in,
                              void* d_out, int out_size, void* d_ws, size_t ws_size,
                              hipStream_t stream)
{
  const float* x    = (const float*)d_in[0];
  const float* sty  = (const float*)d_in[1];
  const float* stq  = (const float*)d_in[2];
  const float* stk  = (const float*)d_in[3];
  const float* stb  = (const float*)d_in[4];
  const float* inW  = (const float*)d_in[5];
  const float* inb  = (const float*)d_in[6];
  const float* py   = (const float*)d_in[7];
  const float* pq   = (const float*)d_in[8];
  const float* pk   = (const float*)d_in[9];
  const float* pb   = (const float*)d_in[10];
  const float* Wo   = (const float*)d_in[11];
  const float* fw1  = (const float*)d_in[12];
  const float* fb1  = (const float*)d_in[13];
  const float* fw2  = (const float*)d_in[14];
  const float* fb2  = (const float*)d_in[15];
  const float* lng  = (const float*)d_in[16];
  const float* lnb  = (const float*)d_in[17];

  char* ws = (char*)d_ws;
  float* h   = (float*)ws;                  // 4 MB (2048 x 512)
  float* xsb = (float*)(ws + (4<<20));      // 4 MB (B,H,S,D)
  float* yb  = (float*)(ws + (8<<20));      // 4 MB (S,B,HID)
  float* t0  = (float*)(ws + (12<<20));     // 4 MB (ln out)
  float* t1  = (float*)(ws + (16<<20));     // 16 MB (2048 x 2048)

  float* out0 = (float*)d_out;
  const size_t OUT_SZ = (size_t)S_SEQ*B_NUM*HID_D;          // 1048576
  const size_t SYL    = (size_t)B_NUM*H_NUM*D_DIM*D_DIM;    // 262144 per layer
  const size_t SBL    = (size_t)B_NUM*H_NUM*D_DIM*4;        // 16384  per layer
  float* o_sy = out0 + OUT_SZ;
  float* o_sq = o_sy + L_NUM*SYL;
  float* o_sk = o_sq + L_NUM*SYL;
  float* o_sb = o_sk + L_NUM*SYL;

  const int M = S_SEQ*B_NUM;   // 2048

  // in-projection: h = x @ in_W.T + in_b
  mgemm_k<true,false,false><<<dim3(HID_D/128, M/128),256,0,stream>>>(
      x, inW, nullptr, inb, h, M, HID_D, 512);

  for (int l=0;l<L_NUM;l++){
    softmax_xs_k<<<(S_SEQ*B_NUM*H_NUM)/4, 256, 0, stream>>>(h, xsb);

    scan4_k<<<B_NUM*H_NUM, 256, 0, stream>>>(xsb,
        sty + (size_t)l*SYL, stq + (size_t)l*SYL, stk + (size_t)l*SYL, stb + (size_t)l*SBL,
        py + (size_t)l*H_NUM*D_DIM*D_DIM, pq + (size_t)l*H_NUM*D_DIM*D_DIM,
        pk + (size_t)l*H_NUM*D_DIM*D_DIM, pb + (size_t)l*H_NUM*D_DIM*4,
        yb,
        o_sy + l*SYL, o_sq + l*SYL, o_sk + l*SYL, o_sb + l*SBL);

    // h += y @ Wo.T
    mgemm_k<false,false,true><<<dim3(HID_D/128, M/128),256,0,stream>>>(
        yb, Wo + (size_t)l*HID_D*HID_D, h, nullptr, h, M, HID_D, HID_D);

    ln_k<<<M/4,256,0,stream>>>(h, lng + l*HID_D, lnb + l*HID_D, t0);

    // t1 = relu(ln @ ff_W1.T + b1)
    mgemm_k<true,true,false><<<dim3(FF_D/128, M/128),256,0,stream>>>(
        t0, fw1 + (size_t)l*FF_D*HID_D, nullptr, fb1 + l*FF_D, t1, M, FF_D, HID_D);

    // h(+out) = h + t1 @ ff_W2.T + b2   (last layer writes d_out directly)
    float* dst = (l==L_NUM-1) ? out0 : h;
    mgemm_k<true,false,true><<<dim3(HID_D/128, M/128),256,0,stream>>>(
        t1, fw2 + (size_t)l*HID_D*FF_D, h, fb2 + l*HID_D, dst, M, HID_D, FF_D);
  }
}